// Round 18
// baseline (1106.653 us; speedup 1.0000x reference)
//
#include <hip/hip_runtime.h>
#include <cstdint>

#define NTOK 8192
#define EDIM 768
#define FDIM 3072

using bf16x8 = __attribute__((ext_vector_type(8))) __bf16;
using f32x4  = __attribute__((ext_vector_type(4))) float;

__device__ __forceinline__ float b2f(ushort u){ union{uint32_t i; float f;} v; v.i = ((uint32_t)u)<<16; return v.f; }
__device__ __forceinline__ ushort f2b(float f){ union{float f; uint32_t i;} v; v.f=f; uint32_t r = v.i + 0x7fffu + ((v.i>>16)&1u); return (ushort)(r>>16); }
__device__ __forceinline__ float gelu_f(float v){
  float c = v*(1.5957691216f + 0.0713548162726f*v*v);
  return v / (1.f + __expf(-c));
}
__device__ __forceinline__ void gload16(const ushort* g, ushort* l){
  __builtin_amdgcn_global_load_lds((const __attribute__((address_space(1))) void*)g,
                                   (__attribute__((address_space(3))) void*)l, 16, 0, 0);
}

// ---------------- weight fp32 -> bf16 pool (LN gains folded into W1 rows) ----------------
__global__ __launch_bounds__(256) void conv_w(const float* w0,const float* w1,const float* w2,
                                              const float* w3,const float* w4,const float* w5,
                                              const float* slg, const float* glg,
                                              ushort* pool)
{
  size_t idx4 = (size_t)blockIdx.x*256 + threadIdx.x;
  size_t e = idx4*4;
  const float* src; size_t base; int region;
  if      (e <  1769472u){src=w0;base=0;        region=0;}
  else if (e <  2359296u){src=w1;base=1769472u; region=1;}
  else if (e <  9437184u){src=w2;base=2359296u; region=2;}
  else if (e < 16515072u){src=w3;base=9437184u; region=3;}
  else if (e < 35389440u){src=w4;base=16515072u;region=4;}
  else                   {src=w5;base=35389440u;region=5;}
  size_t within = e - base;
  f32x4 f = *(const f32x4*)(src + within);
  if (region==2){
    int ex = (int)(within/2359296u); int col = (int)(within%768u);
    f32x4 g = *(const f32x4*)(slg + ex*768 + col);
    f[0]*=g[0]; f[1]*=g[1]; f[2]*=g[2]; f[3]*=g[3];
  } else if (region==4){
    int ex = (int)(within/2359296u); int col = (int)(within%768u);
    f32x4 g = *(const f32x4*)(glg + ex*768 + col);
    f[0]*=g[0]; f[1]*=g[1]; f[2]*=g[2]; f[3]*=g[3];
  }
  ushort4 u; u.x=f2b(f[0]); u.y=f2b(f[1]); u.z=f2b(f[2]); u.w=f2b(f[3]);
  *(ushort4*)(pool+e) = u;
}

__global__ __launch_bounds__(256) void b1fold_k(const float* __restrict__ sw1, const float* __restrict__ gw1,
                                                const float* __restrict__ sb1, const float* __restrict__ gb1,
                                                const float* __restrict__ slb, const float* __restrict__ glb,
                                                float* __restrict__ b1p)
{
  int j = blockIdx.x*4 + (threadIdx.x>>6);
  int lane = threadIdx.x & 63;
  int je = j / FDIM, f = j % FDIM;
  const float* wrow = (je<3) ? sw1 + ((size_t)je*FDIM + f)*EDIM : gw1 + ((size_t)(je-3)*FDIM + f)*EDIM;
  const float* lb   = (je<3) ? slb + (size_t)je*EDIM : glb + (size_t)(je-3)*EDIM;
  float s = 0.f;
  #pragma unroll
  for (int i=0;i<12;i++){ int d = lane + 64*i; s += wrow[d]*lb[d]; }
  #pragma unroll
  for (int o=32;o>0;o>>=1) s += __shfl_xor(s,o);
  if (lane==0){
    float base = (je<3) ? sb1[je*FDIM+f] : gb1[(je-3)*FDIM+f];
    b1p[j] = base + s;
  }
}

__global__ __launch_bounds__(256) void ln1_k(const float* __restrict__ x, const float* __restrict__ g,
                                             const float* __restrict__ b, ushort* __restrict__ out)
{
  int w = blockIdx.x*4 + (threadIdx.x>>6);
  int lane = threadIdx.x & 63;
  const float* xr = x + (size_t)w*EDIM;
  float v[12]; float s=0.f, s2=0.f;
  #pragma unroll
  for (int i=0;i<12;i++){ v[i]=xr[lane+64*i]; s+=v[i]; s2+=v[i]*v[i]; }
  #pragma unroll
  for (int o=32;o>0;o>>=1){ s += __shfl_xor(s,o); s2 += __shfl_xor(s2,o); }
  float mu = s*(1.f/768.f);
  float rs = rsqrtf(s2*(1.f/768.f) - mu*mu + 1e-5f);
  ushort* op = out + (size_t)w*EDIM;
  #pragma unroll
  for (int i=0;i<12;i++){ int d=lane+64*i; op[d] = f2b((v[i]-mu)*rs*g[d] + b[d]); }
}

__global__ __launch_bounds__(256) void lnr_k(const float* __restrict__ x1, const float* __restrict__ g2,
                                             const float* __restrict__ b2, const float* __restrict__ rw,
                                             const float* __restrict__ rbv,
                                             ushort* __restrict__ z, float* __restrict__ coef)
{
  int w = blockIdx.x*4 + (threadIdx.x>>6);
  int lane = threadIdx.x & 63;
  const float* xr = x1 + (size_t)w*EDIM;
  float v[12]; float s=0.f, s2=0.f;
  #pragma unroll
  for (int i=0;i<12;i++){ v[i]=xr[lane+64*i]; s+=v[i]; s2+=v[i]*v[i]; }
  #pragma unroll
  for (int o=32;o>0;o>>=1){ s += __shfl_xor(s,o); s2 += __shfl_xor(s2,o); }
  float mu = s*(1.f/768.f);
  float rs = rsqrtf(s2*(1.f/768.f) - mu*mu + 1e-5f);
  float xn[12]; s=0.f; s2=0.f;
  #pragma unroll
  for (int i=0;i<12;i++){ int d=lane+64*i; xn[i]=(v[i]-mu)*rs*g2[d]+b2[d]; s+=xn[i]; s2+=xn[i]*xn[i]; }
  float pl[8] = {0.f,0.f,0.f,0.f,0.f,0.f,0.f,0.f};
  #pragma unroll
  for (int i=0;i<12;i++){
    int d=lane+64*i; float xv=xn[i];
    #pragma unroll
    for (int e=0;e<8;e++) pl[e] += xv * rw[e*EDIM + d];
  }
  #pragma unroll
  for (int o=32;o>0;o>>=1){ s += __shfl_xor(s,o); s2 += __shfl_xor(s2,o); }
  float mu2 = s*(1.f/768.f);
  float rs2 = rsqrtf(s2*(1.f/768.f) - mu2*mu2 + 1e-5f);
  ushort* op = z + (size_t)w*EDIM;
  #pragma unroll
  for (int i=0;i<12;i++){ int d=lane+64*i; op[d] = f2b((xn[i]-mu2)*rs2); }
  #pragma unroll
  for (int e=0;e<8;e++){
    #pragma unroll
    for (int o=32;o>0;o>>=1) pl[e] += __shfl_xor(pl[e], o);
  }
  float lgt[8]; float mx = -1e30f;
  #pragma unroll
  for (int e=0;e<8;e++){ lgt[e]=pl[e]+rbv[e]; mx = fmaxf(mx, lgt[e]); }
  float p[8]; float den=0.f;
  #pragma unroll
  for (int e=0;e<8;e++){ p[e]=__expf(lgt[e]-mx); den+=p[e]; }
  float inv = 1.f/den;
  #pragma unroll
  for (int e=0;e<8;e++) p[e]*=inv;
  int i1=0;
  #pragma unroll
  for (int e=1;e<8;e++) if (p[e]>p[i1]) i1=e;
  int i2=(i1==0)?1:0;
  #pragma unroll
  for (int e=0;e<8;e++){ if (e==i1) continue; if (p[e]>p[i2]) i2=e; }
  float w1 = 1.f/(1.f+__expf(p[i2]-p[i1]));
  float w2 = 1.f - w1;
  if (lane < 8){
    float c = (lane==i1)? w1 : ((lane==i2)? w2 : 0.f);
    coef[(size_t)w*8 + lane] = c;
  }
}

__global__ __launch_bounds__(256) void build_lists(const int* __restrict__ mt, const float* __restrict__ coef,
                                                   ushort* __restrict__ lists, ushort* __restrict__ inv,
                                                   int* __restrict__ cnt)
{
  const int job = blockIdx.x;
  ushort* list = lists + (size_t)job*NTOK;
  __shared__ int wsum[4];
  int base = 0;
  const int lane = threadIdx.x & 63, wv = threadIdx.x >> 6;
  for (int c0=0; c0<NTOK; c0+=256){
    int t = c0 + threadIdx.x;
    bool flag;
    if (job==0)      flag = (mt[t]==0);
    else if (job==1) flag = (mt[t]==1);
    else             flag = (coef[(size_t)t*8 + (job-2)] != 0.0f);
    unsigned long long bal = __ballot(flag);
    int pre = __popcll(bal & ((1ull<<lane)-1ull));
    if (lane==0) wsum[wv] = __popcll(bal);
    __syncthreads();
    int off = base + pre;
    for (int k=0;k<wv;k++) off += wsum[k];
    int tot = wsum[0]+wsum[1]+wsum[2]+wsum[3];
    if (flag){ list[off] = (ushort)t; inv[(size_t)job*NTOK + t] = (ushort)off; }
    base += tot;
    __syncthreads();
  }
  if (threadIdx.x==0){ cnt[job+1] = base; if (job==0) cnt[0] = NTOK; }
}

__global__ __launch_bounds__(256) void gather_k(const float* __restrict__ coef, const int* __restrict__ mt,
                                                const ushort* __restrict__ inv, const int* __restrict__ cnt,
                                                const ushort* __restrict__ outC, float* __restrict__ out,
                                                int phase)
{
  int t = blockIdx.x*4 + (threadIdx.x>>6);
  int lane = threadIdx.x & 63;
  int r0, r1; float c0=1.f, c1=1.f;
  if (phase==0){
    r0 = t;
    int m = mt[t];
    r1 = NTOK + (m ? cnt[1] : 0) + (int)inv[(size_t)m*NTOK + t];
  } else {
    int found=0; int rr[2]={0,0}; float cc[2]={0.f,0.f}; int base=0;
    #pragma unroll
    for (int e=0;e<8;e++){
      float ce = coef[(size_t)t*8+e];
      if (ce != 0.f && found<2){ rr[found]=base+(int)inv[(size_t)(2+e)*NTOK + t]; cc[found]=ce; found++; }
      base += cnt[3+e];
    }
    r0=rr[0]; r1=rr[1]; c0=cc[0]; c1=cc[1];
  }
  const ushort* pa = outC + (size_t)r0*EDIM;
  const ushort* pb = outC + (size_t)r1*EDIM;
  float* po = out + (size_t)t*EDIM;
  #pragma unroll
  for (int i=0;i<3;i++){
    int d = lane*4 + 256*i;
    ushort4 ua = *(const ushort4*)(pa+d);
    ushort4 ub = *(const ushort4*)(pb+d);
    f32x4 o = *(f32x4*)(po+d);
    o[0] += c0*b2f(ua.x) + c1*b2f(ub.x);
    o[1] += c0*b2f(ua.y) + c1*b2f(ub.y);
    o[2] += c0*b2f(ua.z) + c1*b2f(ub.z);
    o[3] += c0*b2f(ua.w) + c1*b2f(ub.w);
    *(f32x4*)(po+d) = o;
  }
}

// ---------------- dense MFMA GEMM (QKV), 128x128, single-buffer gload ----------------
struct GemmArgs {
  const ushort* A; const ushort* B;
  const float* bias;
  ushort* outBF;
  int K, ldc;
};

__global__ __launch_bounds__(256) void gemm_k(GemmArgs g)
{
  const int mb = blockIdx.x, nb = blockIdx.y;
  __shared__ __align__(1024) ushort As[128*32];
  __shared__ __align__(1024) ushort Bs[128*32];
  const int tid = threadIdx.x;
  const int lane = tid & 63, w = tid >> 6;
  const int seg = lane & 3;
  const int lrow = w*16 + (lane>>2);
  const int p = (lane>>3)&3;
  ushort* ldsA0 = As + (size_t)w*512;
  ushort* ldsA1 = As + (size_t)(w+4)*512;
  ushort* ldsB0 = Bs + (size_t)w*512;
  ushort* ldsB1 = Bs + (size_t)(w+4)*512;
  const int KK = g.K;
  const ushort* pA0 = g.A + (size_t)(mb*128 + lrow)*KK + (seg^p)*8;
  const ushort* pA1 = pA0 + (size_t)64*KK;
  const ushort* pB0 = g.B + (size_t)(nb*128 + lrow)*KK + (seg^p)*8;
  const ushort* pB1 = pB0 + (size_t)64*KK;
  const int nst = KK >> 5;
  f32x4 acc[4][4];
  #pragma unroll
  for (int m=0;m<4;m++)
    #pragma unroll
    for (int n=0;n<4;n++) acc[m][n] = (f32x4){0.f,0.f,0.f,0.f};
  const int fr = lane & 15, fq = lane >> 4;
  const int pr = (fr>>1)&3;
  const int so = (fq^pr)*8;
  const int rb_ = (w>>1)*64, cb_ = (w&1)*64;
  for (int kt=0; kt<nst; ++kt){
    __syncthreads();
    gload16(pA0, ldsA0); gload16(pA1, ldsA1);
    gload16(pB0, ldsB0); gload16(pB1, ldsB1);
    pA0 += 32; pA1 += 32; pB0 += 32; pB1 += 32;
    __syncthreads();
    bf16x8 af[4], bfr[4];
    #pragma unroll
    for (int m=0;m<4;m++) af[m]  = *(const bf16x8*)&As[(rb_ + m*16 + fr)*32 + so];
    #pragma unroll
    for (int n=0;n<4;n++) bfr[n] = *(const bf16x8*)&Bs[(cb_ + n*16 + fr)*32 + so];
    #pragma unroll
    for (int m=0;m<4;m++)
      #pragma unroll
      for (int n=0;n<4;n++)
        acc[m][n] = __builtin_amdgcn_mfma_f32_16x16x32_bf16(af[m], bfr[n], acc[m][n], 0, 0, 0);
  }
  #pragma unroll
  for (int m=0;m<4;m++){
    #pragma unroll
    for (int j=0;j<4;j++){
      const int row = mb*128 + rb_ + m*16 + fq*4 + j;
      #pragma unroll
      for (int n=0;n<4;n++){
        const int col = nb*128 + cb_ + n*16 + fr;
        g.outBF[(size_t)row*g.ldc + col] = f2b(acc[m][n][j] + g.bias[col]);
      }
    }
  }
}

// ---------------- grouped expert FFN kernels ----------------
struct FArgs {
  const ushort* z; ushort* hidden; const ushort* ctx; const ushort* wo;
  float* out; ushort* outC;
  const float* xres; const float* bo;
  const ushort* lists; const ushort* inv; const int* cnt; const float* coef;
  const ushort* sw1; const ushort* gw1; const ushort* sw2; const ushort* gw2;
  const float* b1p; const float* sb2; const float* gb2;
  int jobBase; int compact; int mode; int npanels; int kpx;
};

__device__ __forceinline__ size_t job_hoff(const FArgs& a, int job){
  size_t h = 0;
  if (a.compact){
    if (job==1) h = NTOK;
    else if (job==2) h = NTOK + (size_t)a.cnt[1];
    else if (job>=3){ for (int k=3;k<job;k++) h += (size_t)a.cnt[k]; }
  }
  return h;
}

// FFN1: 128x256 tile, 512 threads, BK=64 (r17 form).
__global__ __launch_bounds__(512) void ffn1_k(FArgs a)
{
  const int bid = blockIdx.x;
  const int xcd = bid & 7;
  const int r = bid >> 3;
  const int pslot = xcd + 8*(r >> 6);
  const int mb = r & 63;
  if (pslot >= a.npanels) return;
  const int jz = pslot / 12;
  const int nb = pslot % 12;
  const int job = a.jobBase + jz;
  const int cntj = (job==0) ? NTOK : a.cnt[job];
  if (mb*128 >= cntj) return;
  const ushort* list = (job==0) ? nullptr : a.lists + (size_t)(job-1)*NTOK;
  const ushort* B = (job<3) ? a.sw1+(size_t)job*FDIM*EDIM : a.gw1+(size_t)(job-3)*FDIM*EDIM;
  const float* bias = a.b1p + (size_t)job*FDIM;
  const size_t hoff = job_hoff(a, job);
  __shared__ __align__(1024) ushort As[128*64];
  __shared__ __align__(1024) ushort Bs[256*64];
  const int tid = threadIdx.x;
  const int lane = tid & 63, w = tid >> 6;
  const int rl = lane >> 3, ch = lane & 7;
  const int chp = ch ^ rl;
  const int arow0 = w*8 + rl, arow1 = 64 + w*8 + rl;
  const int tA0 = list ? (int)list[min(mb*128+arow0, cntj-1)] : min(mb*128+arow0, cntj-1);
  const int tA1 = list ? (int)list[min(mb*128+arow1, cntj-1)] : min(mb*128+arow1, cntj-1);
  const ushort* pA0 = a.z + (size_t)tA0*EDIM + chp*8;
  const ushort* pA1 = a.z + (size_t)tA1*EDIM + chp*8;
  ushort* dA0 = As + (size_t)w*512;
  ushort* dA1 = As + 4096 + (size_t)w*512;
  const ushort* pB0 = B + (size_t)(nb*256 +       w*8 + rl)*EDIM + chp*8;
  const ushort* pB1 = B + (size_t)(nb*256 +  64 + w*8 + rl)*EDIM + chp*8;
  const ushort* pB2 = B + (size_t)(nb*256 + 128 + w*8 + rl)*EDIM + chp*8;
  const ushort* pB3 = B + (size_t)(nb*256 + 192 + w*8 + rl)*EDIM + chp*8;
  ushort* dB0 = Bs + (size_t)w*512;
  ushort* dB1 = Bs +  4096 + (size_t)w*512;
  ushort* dB2 = Bs +  8192 + (size_t)w*512;
  ushort* dB3 = Bs + 12288 + (size_t)w*512;
  f32x4 acc[4][4];
  #pragma unroll
  for (int m=0;m<4;m++)
    #pragma unroll
    for (int n=0;n<4;n++) acc[m][n] = (f32x4){0.f,0.f,0.f,0.f};
  const int fr = lane & 15, fq = lane >> 4;
  const int rb_ = (w>>2)*64;
  const int cb_ = (w&3)*64;
  for (int kt=0; kt<12; ++kt){
    __syncthreads();
    gload16(pA0, dA0); gload16(pA1, dA1);
    gload16(pB0, dB0); gload16(pB1, dB1); gload16(pB2, dB2); gload16(pB3, dB3);
    pA0 += 64; pA1 += 64; pB0 += 64; pB1 += 64; pB2 += 64; pB3 += 64;
    __syncthreads();
    #pragma unroll
    for (int ks=0; ks<2; ++ks){
      const int c = fq + 4*ks;
      bf16x8 af[4], bfr[4];
      #pragma unroll
      for (int m=0;m<4;m++){ int rr = rb_ + m*16 + fr; af[m]  = *(const bf16x8*)&As[rr*64 + ((c^(rr&7))<<3)]; }
      #pragma unroll
      for (int n=0;n<4;n++){ int rr = cb_ + n*16 + fr; bfr[n] = *(const bf16x8*)&Bs[rr*64 + ((c^(rr&7))<<3)]; }
      #pragma unroll
      for (int m=0;m<4;m++)
        #pragma unroll
        for (int n=0;n<4;n++)
          acc[m][n] = __builtin_amdgcn_mfma_f32_16x16x32_bf16(af[m], bfr[n], acc[m][n], 0, 0, 0);
    }
  }
  #pragma unroll
  for (int m=0;m<4;m++){
    #pragma unroll
    for (int j=0;j<4;j++){
      const int row = mb*128 + rb_ + m*16 + fq*4 + j;
      if (row < cntj){
        #pragma unroll
        for (int n=0;n<4;n++){
          const int col = nb*256 + cb_ + n*16 + fr;
          a.hidden[(hoff+row)*FDIM + col] = f2b(gelu_f(acc[m][n][j] + bias[col]));
        }
      }
    }
  }
}

// out-proj only: 64x128 tile, BK=64, dense 2D grid (r16 form)
__global__ __launch_bounds__(256) void ffn2_k(FArgs a)
{
  const int mb = blockIdx.x, nb = blockIdx.y;
  const int lda = EDIM;
  const ushort* Abase = a.ctx;
  const ushort* B = a.wo;
  const int nst = lda >> 6;
  __shared__ __align__(1024) ushort As[64*64];
  __shared__ __align__(1024) ushort Bs[128*64];
  const int tid = threadIdx.x;
  const int lane = tid & 63, w = tid >> 6;
  const int rl = lane >> 3, ch = lane & 7;
  const int chp = ch ^ rl;
  const int ar0 = w*8 + rl, ar1 = 32 + w*8 + rl;
  const ushort* pA0 = Abase + (size_t)(mb*64+ar0)*lda + chp*8;
  const ushort* pA1 = Abase + (size_t)(mb*64+ar1)*lda + chp*8;
  ushort* dA0 = As + (size_t)w*512;
  ushort* dA1 = As + 2048 + (size_t)w*512;
  const ushort* pB0 = B + (size_t)(nb*128 +      w*8 + rl)*lda + chp*8;
  const ushort* pB1 = B + (size_t)(nb*128 + 32 + w*8 + rl)*lda + chp*8;
  const ushort* pB2 = B + (size_t)(nb*128 + 64 + w*8 + rl)*lda + chp*8;
  const ushort* pB3 = B + (size_t)(nb*128 + 96 + w*8 + rl)*lda + chp*8;
  ushort* dB0 = Bs + (size_t)w*512;
  ushort* dB1 = Bs + 2048 + (size_t)w*512;
  ushort* dB2 = Bs + 4096 + (size_t)w*512;
  ushort* dB3 = Bs + 6144 + (size_t)w*512;
  f32x4 acc[4][2];
  #pragma unroll
  for (int m=0;m<4;m++)
    #pragma unroll
    for (int n=0;n<2;n++) acc[m][n] = (f32x4){0.f,0.f,0.f,0.f};
  const int fr = lane & 15, fq = lane >> 4;
  const int cb_ = w*32;
  for (int kt=0; kt<nst; ++kt){
    __syncthreads();
    gload16(pA0, dA0); gload16(pA1, dA1);
    gload16(pB0, dB0); gload16(pB1, dB1); gload16(pB2, dB2); gload16(pB3, dB3);
    pA0 += 64; pA1 += 64; pB0 += 64; pB1 += 64; pB2 += 64; pB3 += 64;
    __syncthreads();
    #pragma unroll
    for (int ks=0; ks<2; ++ks){
      const int c = fq + 4*ks;
      bf16x8 af[4], bfr[2];
      #pragma unroll
      for (int m=0;m<4;m++){ int rr = m*16 + fr;  af[m]  = *(const bf16x8*)&As[rr*64 + ((c^(rr&7))<<3)]; }
      #pragma unroll
      for (int n=0;n<2;n++){ int rr = cb_ + n*16 + fr; bfr[n] = *(const bf16x8*)&Bs[rr*64 + ((c^(rr&7))<<3)]; }
      #pragma unroll
      for (int m=0;m<4;m++)
        #pragma unroll
        for (int n=0;n<2;n++)
          acc[m][n] = __builtin_amdgcn_mfma_f32_16x16x32_bf16(af[m], bfr[n], acc[m][n], 0, 0, 0);
    }
  }
  #pragma unroll
  for (int m=0;m<4;m++){
    #pragma unroll
    for (int j=0;j<4;j++){
      const int row = mb*64 + m*16 + fq*4 + j;
      #pragma unroll
      for (int n=0;n<2;n++){
        const int col = nb*128 + cb_ + n*16 + fr;
        a.out[(size_t)row*EDIM + col] = a.xres[(size_t)row*EDIM + col] + a.bo[col] + acc[m][n][j];
      }
    }
  }
}

// expert FFN2: 64x256 tile, BK=64, XCD-pinned co-streaming decode (3 ntiles/job)
__global__ __launch_bounds__(256) void ffn2w_k(FArgs a)
{
  const int bid = blockIdx.x;
  const int xcd = bid & 7;
  const int r = bid >> 3;
  const int k = r % a.kpx;
  const int mb = r / a.kpx;
  const int pslot = xcd + 8*k;
  if (pslot >= a.npanels) return;
  const int job = a.jobBase + pslot / 3;
  const int nb = pslot % 3;
  const int cntj = (job==0) ? NTOK : a.cnt[job];
  if (mb*64 >= cntj) return;
  const ushort* list = (job==0) ? nullptr : a.lists + (size_t)(job-1)*NTOK;
  const int lda = FDIM;
  const ushort* Abase = a.hidden + job_hoff(a, job)*FDIM;
  const ushort* B; const float* bias; const float* coefp = nullptr; int eidx = 0;
  if (job<3){ B=a.sw2+(size_t)job*(size_t)EDIM*FDIM; bias=a.sb2+(size_t)job*EDIM; }
  else { eidx=job-3; B=a.gw2+(size_t)eidx*(size_t)EDIM*FDIM; bias=a.gb2+(size_t)eidx*EDIM; coefp=a.coef; }
  const int nst = lda >> 6;   // 48
  __shared__ __align__(1024) ushort As[64*64];    // 8 KB
  __shared__ __align__(1024) ushort Bs[256*64];   // 32 KB
  const int tid = threadIdx.x;
  const int lane = tid & 63, w = tid >> 6;
  const int rl = lane >> 3, ch = lane & 7;
  const int chp = ch ^ rl;
  const int ar0 = w*8 + rl, ar1 = 32 + w*8 + rl;
  const ushort* pA0 = Abase + (size_t)min(mb*64+ar0, cntj-1)*lda + chp*8;
  const ushort* pA1 = Abase + (size_t)min(mb*64+ar1, cntj-1)*lda + chp*8;
  ushort* dA0 = As + (size_t)w*512;
  ushort* dA1 = As + 2048 + (size_t)w*512;
  const ushort* pB0 = B + (size_t)(nb*256 +       w*8 + rl)*lda + chp*8;
  const ushort* pB1 = B + (size_t)(nb*256 +  32 + w*8 + rl)*lda + chp*8;
  const ushort* pB2 = B + (size_t)(nb*256 +  64 + w*8 + rl)*lda + chp*8;
  const ushort* pB3 = B + (size_t)(nb*256 +  96 + w*8 + rl)*lda + chp*8;
  const ushort* pB4 = B + (size_t)(nb*256 + 128 + w*8 + rl)*lda + chp*8;
  const ushort* pB5 = B + (size_t)(nb*256 + 160 + w*8 + rl)*lda + chp*8;
  const ushort* pB6 = B + (size_t)(nb*256 + 192 + w*8 + rl)*lda + chp*8;
  const ushort* pB7 = B + (size_t)(nb*256 + 224 + w*8 + rl)*lda + chp*8;
  ushort* dB0 = Bs + (size_t)w*512;
  ushort* dB1 = Bs +  2048 + (size_t)w*512;
  ushort* dB2 = Bs +  4096 + (size_t)w*512;
  ushort* dB3 = Bs +  6144 + (size_t)w*512;
  ushort* dB4 = Bs +  8192 + (size_t)w*512;
  ushort* dB5 = Bs + 10240 + (size_t)w*512;
  ushort* dB6 = Bs + 12288 + (size_t)w*512;
  ushort* dB7 = Bs + 14336 + (size_t)w*512;
  f32x4 acc[4][4];
  #pragma unroll
  for (int m=0;m<4;m++)
    #pragma unroll
    for (int n=0;n<4;n++) acc[m][n] = (f32x4){0.f,0.f,0.f,0.f};
  const int fr = lane & 15, fq = lane >> 4;
  const int cb_ = w*64;
  for (int kt=0; kt<nst; ++kt){
    __syncthreads();
    gload16(pA0, dA0); gload16(pA1, dA1);
    gload16(pB0, dB0); gload16(pB1, dB1); gload16(pB2, dB2); gload16(pB3, dB3);
    gload16(pB4, dB4); gload16(pB5, dB5); gload16(pB6, dB6); gload16(pB7, dB7);
    pA0 += 64; pA1 += 64;
    pB0 += 64; pB1 += 64; pB2 += 64; pB3 += 64;
    pB4 += 64; pB5 += 64; pB6 += 64; pB7 += 64;
    __syncthreads();
    #pragma unroll
    for (int ks=0; ks<2; ++ks){
      const int c = fq + 4*ks;
      bf16x8 af[4], bfr[4];
      #pragma unroll
      for (int m=0;m<4;m++){ int rr = m*16 + fr;       af[m]  = *(const bf16x8*)&As[rr*64 + ((c^(rr&7))<<3)]; }
      #pragma unroll
      for (int n=0;n<4;n++){ int rr = cb_ + n*16 + fr; bfr[n] = *(const bf16x8*)&Bs[rr*64 + ((c^(rr&7))<<3)]; }
      #pragma unroll
      for (int m=0;m<4;m++)
        #pragma unroll
        for (int n=0;n<4;n++)
          acc[m][n] = __builtin_amdgcn_mfma_f32_16x16x32_bf16(af[m], bfr[n], acc[m][n], 0, 0, 0);
    }
  }
  #pragma unroll
  for (int m=0;m<4;m++){
    #pragma unroll
    for (int j=0;j<4;j++){
      const int row = mb*64 + m*16 + fq*4 + j;
      if (row < cntj){
        #pragma unroll
        for (int n=0;n<4;n++){
          const int col = nb*256 + cb_ + n*16 + fr;
          float v = acc[m][n][j] + bias[col];
          if (a.mode==1){
            a.outC[(job_hoff(a,job)+row)*EDIM + col] = f2b(v);
          } else {
            const int tok = list ? (int)list[row] : row;
            const float c = coefp ? coefp[(size_t)tok*8 + eidx] : 1.0f;
            atomicAdd(&a.out[(size_t)tok*EDIM + col], c*v);
          }
        }
      }
    }
  }
}

// ---------------- MFMA flash attention (r13 form) ----------------
__global__ __launch_bounds__(256) void attn_k(const ushort* __restrict__ qkv, ushort* __restrict__ ctx)
{
  const int qb = blockIdx.x, bh = blockIdx.y;
  const int b = bh/12, h = bh%12;
  const int tid = threadIdx.x;
  const int lane = tid & 63, w = tid >> 6;
  const int fr = lane & 15, fq = lane >> 4;
  __shared__ __align__(16) ushort Ks[4096];
  __shared__ __align__(16) ushort Vts[4096];
  __shared__ __align__(16) ushort Ps[4096];
  const size_t tokq = (size_t)b*1024 + (size_t)qb*64;

  bf16x8 qf[2];
  {
    const ushort* qp = qkv + (tokq + w*16 + fr)*2304 + h*64 + fq*8;
    qf[0] = *(const bf16x8*)(qp);
    qf[1] = *(const bf16x8*)(qp + 32);
  }
  f32x4 o[4];
  #pragma unroll
  for (int nt=0;nt<4;nt++) o[nt] = (f32x4){0.f,0.f,0.f,0.f};
  float m[4] = {-1e30f,-1e30f,-1e30f,-1e30f};
  float l[4] = {0.f,0.f,0.f,0.f};

  const int skr = tid>>3, skc = (tid&7)*8;
  const int svd = (tid&15)*4, svk = (tid>>4)*4;

  for (int kt=0; kt<16; ++kt){
    __syncthreads();
    const size_t tokk = (size_t)b*1024 + (size_t)kt*64;
    #pragma unroll
    for (int pp=0;pp<2;pp++){
      int row = skr + pp*32;
      uint4 kq = *(const uint4*)(qkv + (tokk+row)*2304 + 768 + h*64 + skc);
      *(uint4*)&Ks[row*64 + (skc ^ ((row&7)<<3))] = kq;
    }
    {
      union { ushort4 v4[4]; ushort s[16]; } tv;
      #pragma unroll
      for (int i=0;i<4;i++)
        tv.v4[i] = *(const ushort4*)(qkv + (tokk+svk+i)*2304 + 1536 + h*64 + svd);
      #pragma unroll
      for (int j=0;j<4;j++){
        ushort4 tj; tj.x=tv.s[j]; tj.y=tv.s[4+j]; tj.z=tv.s[8+j]; tj.w=tv.s[12+j];
        int dr = svd + j;
        *(ushort4*)&Vts[dr*64 + (svk ^ ((dr&7)<<3))] = tj;
      }
    }
    __syncthreads();
    f32x4 s[4];
    __builtin_amdgcn_s_setprio(1);
    #pragma unroll
    for (int nt=0;nt<4;nt++){
      s[nt] = (f32x4){0.f,0.f,0.f,0.f};
      int kr = nt*16 + fr;
      const ushort* kb = &Ks[kr*64];
      int sw = (kr&7)<<3;
      bf16x8 k0 = *(const bf16x8*)&kb[(fq*8) ^ sw];
      bf16x8 k1 = *(const bf16x8*)&kb[(fq*8+32) ^ sw];
      s[nt] = __builtin_amdgcn_mfma_f32_16x16x32_bf16(qf[0], k0, s[nt], 0,0,0);
      s[nt] = __builtin_amdgcn_mfma_f32_16x16x32_bf16(qf[1], k1, s[nt], 0,0,0);
    }
    __builtin_amdgcn_s_setprio(0);
    float a_[4], pr[4][4];
    #pragma unroll
    for (int j=0;j<4;j++){
      float mx = fmaxf(fmaxf(s[0][j],s[1][j]), fmaxf(s[2][j],s[3][j])) * 0.125f;
      mx = fmaxf(mx, __shfl_xor(mx,1));
      mx = fmaxf(mx, __shfl_xor(mx,2));
      mx = fmaxf(mx, __shfl_xor(mx,4));
      mx = fmaxf(mx, __shfl_xor(mx,8));
      float mn = fmaxf(m[j], mx);
      float aa = __expf(m[j] - mn);
      m[j] = mn; a_[j] = aa;
      float ss = 0.f;
      #pragma unroll
      for (int nt=0;nt<4;nt++){
        float pv = __expf(s[nt][j]*0.125f - mn);
        pr[nt][j] = pv; ss += pv;
      }
      ss += __shfl_xor(ss,1);
      ss += __shfl_xor(ss,2);
      ss += __shfl_xor(ss,4);
      ss += __shfl_xor(ss,8);
      l[j] = l[j]*aa + ss;
    }
    #pragma unroll
    for (int nt=0;nt<4;nt++){
      #pragma unroll
      for (int j=0;j<4;j++){
        int row = fq*4 + j;
        Ps[w*1024 + row*64 + ((nt*16+fr) ^ ((row&7)<<3))] = f2b(pr[nt][j]);
        o[nt][j] *= a_[j];
      }
    }
    __builtin_amdgcn_s_setprio(1);
    #pragma unroll
    for (int ks=0; ks<2; ++ks){
      int kvo = ks*32 + fq*8;
      bf16x8 pf = *(const bf16x8*)&Ps[w*1024 + fr*64 + (kvo ^ ((fr&7)<<3))];
      #pragma unroll
      for (int nt=0;nt<4;nt++){
        int dr = nt*16 + fr;
        bf16x8 vf = *(const bf16x8*)&Vts[dr*64 + (kvo ^ ((dr&7)<<3))];
        o[nt] = __builtin_amdgcn_mfma_f32_16x16x32_bf16(pf, vf, o[nt], 0,0,0);
      }
    }
    __builtin_amdgcn_s_setprio(0);
  }
  float inv[4];
  #pragma unroll
  for (int j=0;j<4;j++) inv[j] = 1.f/l[j];
  ushort* cp = ctx + (tokq + w*16)*768 + h*64;
  #pragma unroll
  for (int nt=0;nt<4;nt++){
    #pragma unroll
    for (int j=0;j<4;j++){
      cp[(size_t)(fq*4+j)*768 + nt*16 + fr] = f2b(o[nt][j]*inv[j]);
    }
  }
}

// ---------------- workspace layout ----------------
#define OFF_POOL   0u
#define OFF_Z      108527616u
#define OFF_COEF   121110528u
#define OFF_LISTS  121372672u
#define OFF_INV    121536512u
#define OFF_CNT    121700352u
#define OFF_B1P    121700608u
#define OFF_QKV    121835776u
#define OFF_CTX    159584512u
#define OFF_XN1    172167424u
#define WS_GROUPED 222499072u
#define OFF_OUTC   222499072u
#define WS_BIG     247664896u

extern "C" void kernel_launch(void* const* d_in, const int* in_sizes, int n_in,
                              void* d_out, int out_size, void* d_ws, size_t ws_size,
                              hipStream_t stream)
{
  const float* x    = (const float*)d_in[0];
  const int*   mt   = (const int*)d_in[1];
  const float* n1g  = (const float*)d_in[2];
  const float* n1b  = (const float*)d_in[3];
  const float* n2g  = (const float*)d_in[4];
  const float* n2b  = (const float*)d_in[5];
  const float* wqkv = (const float*)d_in[6];
  const float* bqkv = (const float*)d_in[7];
  const float* wo   = (const float*)d_in[8];
  const float* bo   = (const float*)d_in[9];
  const float* rw   = (const float*)d_in[10];
  const float* rb   = (const float*)d_in[11];
  const float* slg  = (const float*)d_in[12];
  const float* slb  = (const float*)d_in[13];
  const float* sw1  = (const float*)d_in[14];
  const float* sb1  = (const float*)d_in[15];
  const float* sw2  = (const float*)d_in[16];
  const float* sb2  = (const float*)d_in[17];
  const float* glg  = (const float*)d_in[18];
  const float* glb  = (const float*)d_in[19];
  const float* gw1  = (const float*)d_in[20];
  const float* gb1  = (const float*)d_in[21];
  const float* gw2  = (const float*)d_in[22];
  const float* gb2  = (const float*)d_in[23];
  float* out = (float*)d_out;
  char* ws = (char*)d_ws;

  ushort* pool  = (ushort*)(ws + OFF_POOL);
  ushort* z     = (ushort*)(ws + OFF_Z);
  float*  coef  = (float*) (ws + OFF_COEF);
  ushort* lists = (ushort*)(ws + OFF_LISTS);
  ushort* invp  = (ushort*)(ws + OFF_INV);
  int*    cnt   = (int*)   (ws + OFF_CNT);
  float*  b1p   = (float*) (ws + OFF_B1P);
  ushort* qkv   = (ushort*)(ws + OFF_QKV);
  ushort* ctx   = (ushort*)(ws + OFF_CTX);
  ushort* xn1   = (ushort*)(ws + OFF_XN1);
  ushort* hidden= (ushort*)(ws + OFF_QKV);
  ushort* outC  = (ushort*)(ws + OFF_OUTC);

  ushort* pWqkv = pool + 0;
  ushort* pWo   = pool + 1769472;
  ushort* pSw1  = pool + 2359296;
  ushort* pSw2  = pool + 9437184;
  ushort* pGw1  = pool + 16515072;
  ushort* pGw2  = pool + 35389440;

  const int tier = (ws_size >= (size_t)WS_BIG) ? 2 : ((ws_size >= (size_t)WS_GROUPED) ? 1 : 0);

  conv_w<<<52992, 256, 0, stream>>>(wqkv, wo, sw1, sw2, gw1, gw2, slg, glg, pool);
  b1fold_k<<<8448, 256, 0, stream>>>(sw1, gw1, sb1, gb1, slb, glb, b1p);
  ln1_k<<<2048, 256, 0, stream>>>(x, n1g, n1b, xn1);
  { GemmArgs a{}; a.A=xn1; a.B=pWqkv; a.bias=bqkv; a.outBF=qkv; a.K=768; a.ldc=2304;
    gemm_k<<<dim3(64,18),256,0,stream>>>(a); }
  attn_k<<<dim3(16,96),256,0,stream>>>(qkv, ctx);

  FArgs fa{};
  fa.z=z; fa.hidden=hidden; fa.ctx=ctx; fa.wo=pWo; fa.out=out; fa.outC=outC;
  fa.xres=x; fa.bo=bo;
  fa.lists=lists; fa.inv=invp; fa.cnt=cnt; fa.coef=coef;
  fa.sw1=pSw1; fa.gw1=pGw1; fa.sw2=pSw2; fa.gw2=pGw2;
  fa.b1p=b1p; fa.sb2=sb2; fa.gb2=gb2;

  // out-proj with fused residual+bias: dense 2D grid
  { FArgs a = fa; a.jobBase = -1;
    ffn2_k<<<dim3(128,6),256,0,stream>>>(a); }

  lnr_k<<<2048,256,0,stream>>>(out, n2g, n2b, rw, rb, z, coef);
  build_lists<<<10,256,0,stream>>>(mt, coef, lists, invp, cnt);

  if (tier==2){
    { FArgs a = fa; a.jobBase = 0; a.compact = 1; a.mode = 1;
      a.npanels = 36; ffn1_k<<<2560,512,0,stream>>>(a);
      a.npanels = 9;  a.kpx = 2; ffn2w_k<<<2048,256,0,stream>>>(a); }   // 8*2*128
    gather_k<<<2048,256,0,stream>>>(coef, mt, invp, cnt, outC, out, 0);
    { FArgs a = fa; a.jobBase = 3; a.compact = 1; a.mode = 1;
      a.npanels = 96; ffn1_k<<<6144,512,0,stream>>>(a);
      a.npanels = 24; a.kpx = 3; ffn2w_k<<<3072,256,0,stream>>>(a); }   // 8*3*128
    gather_k<<<2048,256,0,stream>>>(coef, mt, invp, cnt, outC, out, 1);
  } else if (tier==1){
    { FArgs a = fa; a.jobBase = 0; a.compact = 1; a.mode = 0;
      a.npanels = 36; ffn1_k<<<2560,512,0,stream>>>(a);
      a.npanels = 9;  a.kpx = 2; ffn2w_k<<<2048,256,0,stream>>>(a); }
    { FArgs a = fa; a.jobBase = 3; a.compact = 1; a.mode = 0;
      a.npanels = 96; ffn1_k<<<6144,512,0,stream>>>(a);
      a.npanels = 24; a.kpx = 3; ffn2w_k<<<3072,256,0,stream>>>(a); }
  } else {
    for (int j=0;j<11;j++){
      FArgs a = fa; a.jobBase = j; a.compact = 0; a.mode = 0;
      a.npanels = 12; ffn1_k<<<1024,512,0,stream>>>(a);
      a.npanels = 3;  a.kpx = 1; ffn2w_k<<<1024,256,0,stream>>>(a);
    }
  }
}

// Round 19
// 952.918 us; speedup vs baseline: 1.1613x; 1.1613x over previous
//
#include <hip/hip_runtime.h>
#include <cstdint>

#define NTOK 8192
#define EDIM 768
#define FDIM 3072

using bf16x8 = __attribute__((ext_vector_type(8))) __bf16;
using f32x4  = __attribute__((ext_vector_type(4))) float;

__device__ __forceinline__ float b2f(ushort u){ union{uint32_t i; float f;} v; v.i = ((uint32_t)u)<<16; return v.f; }
__device__ __forceinline__ ushort f2b(float f){ union{float f; uint32_t i;} v; v.f=f; uint32_t r = v.i + 0x7fffu + ((v.i>>16)&1u); return (ushort)(r>>16); }
__device__ __forceinline__ float gelu_f(float v){
  float c = v*(1.5957691216f + 0.0713548162726f*v*v);
  return v / (1.f + __expf(-c));
}
__device__ __forceinline__ void gload16(const ushort* g, ushort* l){
  __builtin_amdgcn_global_load_lds((const __attribute__((address_space(1))) void*)g,
                                   (__attribute__((address_space(3))) void*)l, 16, 0, 0);
}

// ---------------- weight fp32 -> bf16 pool (LN gains folded into W1 rows) ----------------
__global__ __launch_bounds__(256) void conv_w(const float* w0,const float* w1,const float* w2,
                                              const float* w3,const float* w4,const float* w5,
                                              const float* slg, const float* glg,
                                              ushort* pool)
{
  size_t idx4 = (size_t)blockIdx.x*256 + threadIdx.x;
  size_t e = idx4*4;
  const float* src; size_t base; int region;
  if      (e <  1769472u){src=w0;base=0;        region=0;}
  else if (e <  2359296u){src=w1;base=1769472u; region=1;}
  else if (e <  9437184u){src=w2;base=2359296u; region=2;}
  else if (e < 16515072u){src=w3;base=9437184u; region=3;}
  else if (e < 35389440u){src=w4;base=16515072u;region=4;}
  else                   {src=w5;base=35389440u;region=5;}
  size_t within = e - base;
  f32x4 f = *(const f32x4*)(src + within);
  if (region==2){
    int ex = (int)(within/2359296u); int col = (int)(within%768u);
    f32x4 g = *(const f32x4*)(slg + ex*768 + col);
    f[0]*=g[0]; f[1]*=g[1]; f[2]*=g[2]; f[3]*=g[3];
  } else if (region==4){
    int ex = (int)(within/2359296u); int col = (int)(within%768u);
    f32x4 g = *(const f32x4*)(glg + ex*768 + col);
    f[0]*=g[0]; f[1]*=g[1]; f[2]*=g[2]; f[3]*=g[3];
  }
  ushort4 u; u.x=f2b(f[0]); u.y=f2b(f[1]); u.z=f2b(f[2]); u.w=f2b(f[3]);
  *(ushort4*)(pool+e) = u;
}

__global__ __launch_bounds__(256) void b1fold_k(const float* __restrict__ sw1, const float* __restrict__ gw1,
                                                const float* __restrict__ sb1, const float* __restrict__ gb1,
                                                const float* __restrict__ slb, const float* __restrict__ glb,
                                                float* __restrict__ b1p)
{
  int j = blockIdx.x*4 + (threadIdx.x>>6);
  int lane = threadIdx.x & 63;
  int je = j / FDIM, f = j % FDIM;
  const float* wrow = (je<3) ? sw1 + ((size_t)je*FDIM + f)*EDIM : gw1 + ((size_t)(je-3)*FDIM + f)*EDIM;
  const float* lb   = (je<3) ? slb + (size_t)je*EDIM : glb + (size_t)(je-3)*EDIM;
  float s = 0.f;
  #pragma unroll
  for (int i=0;i<12;i++){ int d = lane + 64*i; s += wrow[d]*lb[d]; }
  #pragma unroll
  for (int o=32;o>0;o>>=1) s += __shfl_xor(s,o);
  if (lane==0){
    float base = (je<3) ? sb1[je*FDIM+f] : gb1[(je-3)*FDIM+f];
    b1p[j] = base + s;
  }
}

__global__ __launch_bounds__(256) void ln1_k(const float* __restrict__ x, const float* __restrict__ g,
                                             const float* __restrict__ b, ushort* __restrict__ out)
{
  int w = blockIdx.x*4 + (threadIdx.x>>6);
  int lane = threadIdx.x & 63;
  const float* xr = x + (size_t)w*EDIM;
  float v[12]; float s=0.f, s2=0.f;
  #pragma unroll
  for (int i=0;i<12;i++){ v[i]=xr[lane+64*i]; s+=v[i]; s2+=v[i]*v[i]; }
  #pragma unroll
  for (int o=32;o>0;o>>=1){ s += __shfl_xor(s,o); s2 += __shfl_xor(s2,o); }
  float mu = s*(1.f/768.f);
  float rs = rsqrtf(s2*(1.f/768.f) - mu*mu + 1e-5f);
  ushort* op = out + (size_t)w*EDIM;
  #pragma unroll
  for (int i=0;i<12;i++){ int d=lane+64*i; op[d] = f2b((v[i]-mu)*rs*g[d] + b[d]); }
}

__global__ __launch_bounds__(256) void lnr_k(const float* __restrict__ x1, const float* __restrict__ g2,
                                             const float* __restrict__ b2, const float* __restrict__ rw,
                                             const float* __restrict__ rbv,
                                             ushort* __restrict__ z, float* __restrict__ coef)
{
  int w = blockIdx.x*4 + (threadIdx.x>>6);
  int lane = threadIdx.x & 63;
  const float* xr = x1 + (size_t)w*EDIM;
  float v[12]; float s=0.f, s2=0.f;
  #pragma unroll
  for (int i=0;i<12;i++){ v[i]=xr[lane+64*i]; s+=v[i]; s2+=v[i]*v[i]; }
  #pragma unroll
  for (int o=32;o>0;o>>=1){ s += __shfl_xor(s,o); s2 += __shfl_xor(s2,o); }
  float mu = s*(1.f/768.f);
  float rs = rsqrtf(s2*(1.f/768.f) - mu*mu + 1e-5f);
  float xn[12]; s=0.f; s2=0.f;
  #pragma unroll
  for (int i=0;i<12;i++){ int d=lane+64*i; xn[i]=(v[i]-mu)*rs*g2[d]+b2[d]; s+=xn[i]; s2+=xn[i]*xn[i]; }
  float pl[8] = {0.f,0.f,0.f,0.f,0.f,0.f,0.f,0.f};
  #pragma unroll
  for (int i=0;i<12;i++){
    int d=lane+64*i; float xv=xn[i];
    #pragma unroll
    for (int e=0;e<8;e++) pl[e] += xv * rw[e*EDIM + d];
  }
  #pragma unroll
  for (int o=32;o>0;o>>=1){ s += __shfl_xor(s,o); s2 += __shfl_xor(s2,o); }
  float mu2 = s*(1.f/768.f);
  float rs2 = rsqrtf(s2*(1.f/768.f) - mu2*mu2 + 1e-5f);
  ushort* op = z + (size_t)w*EDIM;
  #pragma unroll
  for (int i=0;i<12;i++){ int d=lane+64*i; op[d] = f2b((xn[i]-mu2)*rs2); }
  #pragma unroll
  for (int e=0;e<8;e++){
    #pragma unroll
    for (int o=32;o>0;o>>=1) pl[e] += __shfl_xor(pl[e], o);
  }
  float lgt[8]; float mx = -1e30f;
  #pragma unroll
  for (int e=0;e<8;e++){ lgt[e]=pl[e]+rbv[e]; mx = fmaxf(mx, lgt[e]); }
  float p[8]; float den=0.f;
  #pragma unroll
  for (int e=0;e<8;e++){ p[e]=__expf(lgt[e]-mx); den+=p[e]; }
  float inv = 1.f/den;
  #pragma unroll
  for (int e=0;e<8;e++) p[e]*=inv;
  int i1=0;
  #pragma unroll
  for (int e=1;e<8;e++) if (p[e]>p[i1]) i1=e;
  int i2=(i1==0)?1:0;
  #pragma unroll
  for (int e=0;e<8;e++){ if (e==i1) continue; if (p[e]>p[i2]) i2=e; }
  float w1 = 1.f/(1.f+__expf(p[i2]-p[i1]));
  float w2 = 1.f - w1;
  if (lane < 8){
    float c = (lane==i1)? w1 : ((lane==i2)? w2 : 0.f);
    coef[(size_t)w*8 + lane] = c;
  }
}

__global__ __launch_bounds__(256) void build_lists(const int* __restrict__ mt, const float* __restrict__ coef,
                                                   ushort* __restrict__ lists, ushort* __restrict__ inv,
                                                   int* __restrict__ cnt)
{
  const int job = blockIdx.x;
  ushort* list = lists + (size_t)job*NTOK;
  __shared__ int wsum[4];
  int base = 0;
  const int lane = threadIdx.x & 63, wv = threadIdx.x >> 6;
  for (int c0=0; c0<NTOK; c0+=256){
    int t = c0 + threadIdx.x;
    bool flag;
    if (job==0)      flag = (mt[t]==0);
    else if (job==1) flag = (mt[t]==1);
    else             flag = (coef[(size_t)t*8 + (job-2)] != 0.0f);
    unsigned long long bal = __ballot(flag);
    int pre = __popcll(bal & ((1ull<<lane)-1ull));
    if (lane==0) wsum[wv] = __popcll(bal);
    __syncthreads();
    int off = base + pre;
    for (int k=0;k<wv;k++) off += wsum[k];
    int tot = wsum[0]+wsum[1]+wsum[2]+wsum[3];
    if (flag){ list[off] = (ushort)t; inv[(size_t)job*NTOK + t] = (ushort)off; }
    base += tot;
    __syncthreads();
  }
  if (threadIdx.x==0){ cnt[job+1] = base; if (job==0) cnt[0] = NTOK; }
}

__global__ __launch_bounds__(256) void gather_k(const float* __restrict__ coef, const int* __restrict__ mt,
                                                const ushort* __restrict__ inv, const int* __restrict__ cnt,
                                                const ushort* __restrict__ outC, float* __restrict__ out,
                                                int phase)
{
  int t = blockIdx.x*4 + (threadIdx.x>>6);
  int lane = threadIdx.x & 63;
  int r0, r1; float c0=1.f, c1=1.f;
  if (phase==0){
    r0 = t;
    int m = mt[t];
    r1 = NTOK + (m ? cnt[1] : 0) + (int)inv[(size_t)m*NTOK + t];
  } else {
    int found=0; int rr[2]={0,0}; float cc[2]={0.f,0.f}; int base=0;
    #pragma unroll
    for (int e=0;e<8;e++){
      float ce = coef[(size_t)t*8+e];
      if (ce != 0.f && found<2){ rr[found]=base+(int)inv[(size_t)(2+e)*NTOK + t]; cc[found]=ce; found++; }
      base += cnt[3+e];
    }
    r0=rr[0]; r1=rr[1]; c0=cc[0]; c1=cc[1];
  }
  const ushort* pa = outC + (size_t)r0*EDIM;
  const ushort* pb = outC + (size_t)r1*EDIM;
  float* po = out + (size_t)t*EDIM;
  #pragma unroll
  for (int i=0;i<3;i++){
    int d = lane*4 + 256*i;
    ushort4 ua = *(const ushort4*)(pa+d);
    ushort4 ub = *(const ushort4*)(pb+d);
    f32x4 o = *(f32x4*)(po+d);
    o[0] += c0*b2f(ua.x) + c1*b2f(ub.x);
    o[1] += c0*b2f(ua.y) + c1*b2f(ub.y);
    o[2] += c0*b2f(ua.z) + c1*b2f(ub.z);
    o[3] += c0*b2f(ua.w) + c1*b2f(ub.w);
    *(f32x4*)(po+d) = o;
  }
}

// ---------------- dense MFMA GEMM (QKV), 128x128, single-buffer gload ----------------
struct GemmArgs {
  const ushort* A; const ushort* B;
  const float* bias;
  ushort* outBF;
  int K, ldc;
};

__global__ __launch_bounds__(256) void gemm_k(GemmArgs g)
{
  const int mb = blockIdx.x, nb = blockIdx.y;
  __shared__ __align__(1024) ushort As[128*32];
  __shared__ __align__(1024) ushort Bs[128*32];
  const int tid = threadIdx.x;
  const int lane = tid & 63, w = tid >> 6;
  const int seg = lane & 3;
  const int lrow = w*16 + (lane>>2);
  const int p = (lane>>3)&3;
  ushort* ldsA0 = As + (size_t)w*512;
  ushort* ldsA1 = As + (size_t)(w+4)*512;
  ushort* ldsB0 = Bs + (size_t)w*512;
  ushort* ldsB1 = Bs + (size_t)(w+4)*512;
  const int KK = g.K;
  const ushort* pA0 = g.A + (size_t)(mb*128 + lrow)*KK + (seg^p)*8;
  const ushort* pA1 = pA0 + (size_t)64*KK;
  const ushort* pB0 = g.B + (size_t)(nb*128 + lrow)*KK + (seg^p)*8;
  const ushort* pB1 = pB0 + (size_t)64*KK;
  const int nst = KK >> 5;
  f32x4 acc[4][4];
  #pragma unroll
  for (int m=0;m<4;m++)
    #pragma unroll
    for (int n=0;n<4;n++) acc[m][n] = (f32x4){0.f,0.f,0.f,0.f};
  const int fr = lane & 15, fq = lane >> 4;
  const int pr = (fr>>1)&3;
  const int so = (fq^pr)*8;
  const int rb_ = (w>>1)*64, cb_ = (w&1)*64;
  for (int kt=0; kt<nst; ++kt){
    __syncthreads();
    gload16(pA0, ldsA0); gload16(pA1, ldsA1);
    gload16(pB0, ldsB0); gload16(pB1, ldsB1);
    pA0 += 32; pA1 += 32; pB0 += 32; pB1 += 32;
    __syncthreads();
    bf16x8 af[4], bfr[4];
    #pragma unroll
    for (int m=0;m<4;m++) af[m]  = *(const bf16x8*)&As[(rb_ + m*16 + fr)*32 + so];
    #pragma unroll
    for (int n=0;n<4;n++) bfr[n] = *(const bf16x8*)&Bs[(cb_ + n*16 + fr)*32 + so];
    #pragma unroll
    for (int m=0;m<4;m++)
      #pragma unroll
      for (int n=0;n<4;n++)
        acc[m][n] = __builtin_amdgcn_mfma_f32_16x16x32_bf16(af[m], bfr[n], acc[m][n], 0, 0, 0);
  }
  #pragma unroll
  for (int m=0;m<4;m++){
    #pragma unroll
    for (int j=0;j<4;j++){
      const int row = mb*128 + rb_ + m*16 + fq*4 + j;
      #pragma unroll
      for (int n=0;n<4;n++){
        const int col = nb*128 + cb_ + n*16 + fr;
        g.outBF[(size_t)row*g.ldc + col] = f2b(acc[m][n][j] + g.bias[col]);
      }
    }
  }
}

// ---------------- grouped expert FFN kernels ----------------
struct FArgs {
  const ushort* z; ushort* hidden; const ushort* ctx; const ushort* wo;
  float* out; ushort* outC;
  const float* xres; const float* bo;
  const ushort* lists; const ushort* inv; const int* cnt; const float* coef;
  const ushort* sw1; const ushort* gw1; const ushort* sw2; const ushort* gw2;
  const float* b1p; const float* sb2; const float* gb2;
  int jobBase; int compact; int mode; int npanels; int kpx;
};

__device__ __forceinline__ size_t job_hoff(const FArgs& a, int job){
  size_t h = 0;
  if (a.compact){
    if (job==1) h = NTOK;
    else if (job==2) h = NTOK + (size_t)a.cnt[1];
    else if (job>=3){ for (int k=3;k<job;k++) h += (size_t)a.cnt[k]; }
  }
  return h;
}

// FFN1: 128x256 tile, 512 threads (8 waves, 2x4), BK=64, single-buffer gload.
// LDS [rows][64] bf16; stage chunk' = ch ^ rl on GLOBAL src (rows 8k+rl), linear LDS dest; read XOR matches.
__global__ __launch_bounds__(512) void ffn1_k(FArgs a)
{
  const int bid = blockIdx.x;
  const int xcd = bid & 7;
  const int r = bid >> 3;
  const int pslot = xcd + 8*(r >> 6);
  const int mb = r & 63;
  if (pslot >= a.npanels) return;
  const int jz = pslot / 12;
  const int nb = pslot % 12;
  const int job = a.jobBase + jz;
  const int cntj = (job==0) ? NTOK : a.cnt[job];
  if (mb*128 >= cntj) return;
  const ushort* list = (job==0) ? nullptr : a.lists + (size_t)(job-1)*NTOK;
  const ushort* B = (job<3) ? a.sw1+(size_t)job*FDIM*EDIM : a.gw1+(size_t)(job-3)*FDIM*EDIM;
  const float* bias = a.b1p + (size_t)job*FDIM;
  const size_t hoff = job_hoff(a, job);
  __shared__ __align__(1024) ushort As[128*64];   // 16 KB
  __shared__ __align__(1024) ushort Bs[256*64];   // 32 KB
  const int tid = threadIdx.x;
  const int lane = tid & 63, w = tid >> 6;        // 8 waves
  const int rl = lane >> 3, ch = lane & 7;
  const int chp = ch ^ rl;
  // A rows: w*8+rl and 64+w*8+rl (gathered tokens)
  const int arow0 = w*8 + rl, arow1 = 64 + w*8 + rl;
  const int tA0 = list ? (int)list[min(mb*128+arow0, cntj-1)] : min(mb*128+arow0, cntj-1);
  const int tA1 = list ? (int)list[min(mb*128+arow1, cntj-1)] : min(mb*128+arow1, cntj-1);
  const ushort* pA0 = a.z + (size_t)tA0*EDIM + chp*8;
  const ushort* pA1 = a.z + (size_t)tA1*EDIM + chp*8;
  ushort* dA0 = As + (size_t)w*512;
  ushort* dA1 = As + 4096 + (size_t)w*512;
  // B rows: i*64 + w*8 + rl, i=0..3
  const ushort* pB0 = B + (size_t)(nb*256 +       w*8 + rl)*EDIM + chp*8;
  const ushort* pB1 = B + (size_t)(nb*256 +  64 + w*8 + rl)*EDIM + chp*8;
  const ushort* pB2 = B + (size_t)(nb*256 + 128 + w*8 + rl)*EDIM + chp*8;
  const ushort* pB3 = B + (size_t)(nb*256 + 192 + w*8 + rl)*EDIM + chp*8;
  ushort* dB0 = Bs + (size_t)w*512;
  ushort* dB1 = Bs +  4096 + (size_t)w*512;
  ushort* dB2 = Bs +  8192 + (size_t)w*512;
  ushort* dB3 = Bs + 12288 + (size_t)w*512;
  f32x4 acc[4][4];
  #pragma unroll
  for (int m=0;m<4;m++)
    #pragma unroll
    for (int n=0;n<4;n++) acc[m][n] = (f32x4){0.f,0.f,0.f,0.f};
  const int fr = lane & 15, fq = lane >> 4;
  const int rb_ = (w>>2)*64;
  const int cb_ = (w&3)*64;
  for (int kt=0; kt<12; ++kt){
    __syncthreads();
    gload16(pA0, dA0); gload16(pA1, dA1);
    gload16(pB0, dB0); gload16(pB1, dB1); gload16(pB2, dB2); gload16(pB3, dB3);
    pA0 += 64; pA1 += 64; pB0 += 64; pB1 += 64; pB2 += 64; pB3 += 64;
    __syncthreads();
    #pragma unroll
    for (int ks=0; ks<2; ++ks){
      const int c = fq + 4*ks;
      bf16x8 af[4], bfr[4];
      #pragma unroll
      for (int m=0;m<4;m++){ int rr = rb_ + m*16 + fr; af[m]  = *(const bf16x8*)&As[rr*64 + ((c^(rr&7))<<3)]; }
      #pragma unroll
      for (int n=0;n<4;n++){ int rr = cb_ + n*16 + fr; bfr[n] = *(const bf16x8*)&Bs[rr*64 + ((c^(rr&7))<<3)]; }
      #pragma unroll
      for (int m=0;m<4;m++)
        #pragma unroll
        for (int n=0;n<4;n++)
          acc[m][n] = __builtin_amdgcn_mfma_f32_16x16x32_bf16(af[m], bfr[n], acc[m][n], 0, 0, 0);
    }
  }
  #pragma unroll
  for (int m=0;m<4;m++){
    #pragma unroll
    for (int j=0;j<4;j++){
      const int row = mb*128 + rb_ + m*16 + fq*4 + j;
      if (row < cntj){
        #pragma unroll
        for (int n=0;n<4;n++){
          const int col = nb*256 + cb_ + n*16 + fr;
          a.hidden[(hoff+row)*FDIM + col] = f2b(gelu_f(acc[m][n][j] + bias[col]));
        }
      }
    }
  }
}

// FFN2 / out-proj: 64x128 tile, BK=64, single-buffer gload (r16 form).
__global__ __launch_bounds__(256) void ffn2_k(FArgs a)
{
  const bool op = (a.jobBase < 0);
  int mb, nb, job;
  if (op){
    mb = blockIdx.x; nb = blockIdx.y; job = -1;
  } else {
    const int bid = blockIdx.x;
    const int xcd = bid & 7;
    const int r = bid >> 3;
    const int k = r % a.kpx;
    mb = r / a.kpx;
    const int pslot = xcd + 8*k;
    if (pslot >= a.npanels) return;
    job = a.jobBase + pslot / 6;
    nb = pslot % 6;
  }
  const int cntj = op ? NTOK : ((job==0) ? NTOK : a.cnt[job]);
  if (mb*64 >= cntj) return;
  const ushort* list = (op || job==0) ? nullptr : a.lists + (size_t)(job-1)*NTOK;
  const ushort* Abase; int lda; const ushort* B; const float* bias = nullptr;
  const float* coefp = nullptr; int eidx = 0;
  if (op){ Abase = a.ctx; lda = EDIM; B = a.wo; }
  else {
    lda = FDIM;
    Abase = a.hidden + job_hoff(a, job)*FDIM;
    if (job<3){ B=a.sw2+(size_t)job*(size_t)EDIM*FDIM; bias=a.sb2+(size_t)job*EDIM; }
    else { eidx=job-3; B=a.gw2+(size_t)eidx*(size_t)EDIM*FDIM; bias=a.gb2+(size_t)eidx*EDIM; coefp=a.coef; }
  }
  const int nst = lda >> 6;
  __shared__ __align__(1024) ushort As[64*64];
  __shared__ __align__(1024) ushort Bs[128*64];
  const int tid = threadIdx.x;
  const int lane = tid & 63, w = tid >> 6;
  const int rl = lane >> 3, ch = lane & 7;
  const int chp = ch ^ rl;
  const int ar0 = w*8 + rl, ar1 = 32 + w*8 + rl;
  const ushort* pA0 = Abase + (size_t)min(mb*64+ar0, cntj-1)*lda + chp*8;
  const ushort* pA1 = Abase + (size_t)min(mb*64+ar1, cntj-1)*lda + chp*8;
  ushort* dA0 = As + (size_t)w*512;
  ushort* dA1 = As + 2048 + (size_t)w*512;
  const ushort* pB0 = B + (size_t)(nb*128 +      w*8 + rl)*lda + chp*8;
  const ushort* pB1 = B + (size_t)(nb*128 + 32 + w*8 + rl)*lda + chp*8;
  const ushort* pB2 = B + (size_t)(nb*128 + 64 + w*8 + rl)*lda + chp*8;
  const ushort* pB3 = B + (size_t)(nb*128 + 96 + w*8 + rl)*lda + chp*8;
  ushort* dB0 = Bs + (size_t)w*512;
  ushort* dB1 = Bs + 2048 + (size_t)w*512;
  ushort* dB2 = Bs + 4096 + (size_t)w*512;
  ushort* dB3 = Bs + 6144 + (size_t)w*512;
  f32x4 acc[4][2];
  #pragma unroll
  for (int m=0;m<4;m++)
    #pragma unroll
    for (int n=0;n<2;n++) acc[m][n] = (f32x4){0.f,0.f,0.f,0.f};
  const int fr = lane & 15, fq = lane >> 4;
  const int cb_ = w*32;
  for (int kt=0; kt<nst; ++kt){
    __syncthreads();
    gload16(pA0, dA0); gload16(pA1, dA1);
    gload16(pB0, dB0); gload16(pB1, dB1); gload16(pB2, dB2); gload16(pB3, dB3);
    pA0 += 64; pA1 += 64; pB0 += 64; pB1 += 64; pB2 += 64; pB3 += 64;
    __syncthreads();
    #pragma unroll
    for (int ks=0; ks<2; ++ks){
      const int c = fq + 4*ks;
      bf16x8 af[4], bfr[2];
      #pragma unroll
      for (int m=0;m<4;m++){ int rr = m*16 + fr;  af[m]  = *(const bf16x8*)&As[rr*64 + ((c^(rr&7))<<3)]; }
      #pragma unroll
      for (int n=0;n<2;n++){ int rr = cb_ + n*16 + fr; bfr[n] = *(const bf16x8*)&Bs[rr*64 + ((c^(rr&7))<<3)]; }
      #pragma unroll
      for (int m=0;m<4;m++)
        #pragma unroll
        for (int n=0;n<2;n++)
          acc[m][n] = __builtin_amdgcn_mfma_f32_16x16x32_bf16(af[m], bfr[n], acc[m][n], 0, 0, 0);
    }
  }
  #pragma unroll
  for (int m=0;m<4;m++){
    #pragma unroll
    for (int j=0;j<4;j++){
      const int row = mb*64 + m*16 + fq*4 + j;
      if (row < cntj){
        #pragma unroll
        for (int n=0;n<2;n++){
          const int col = nb*128 + cb_ + n*16 + fr;
          float v = acc[m][n][j];
          if (op){
            a.out[(size_t)row*EDIM + col] = a.xres[(size_t)row*EDIM + col] + a.bo[col] + v;
          } else if (a.mode==1){
            a.outC[(job_hoff(a,job)+row)*EDIM + col] = f2b(v + bias[col]);
          } else {
            const int tok = list ? (int)list[row] : row;
            const float c = coefp ? coefp[(size_t)tok*8 + eidx] : 1.0f;
            atomicAdd(&a.out[(size_t)tok*EDIM + col], c*(v + bias[col]));
          }
        }
      }
    }
  }
}

// ---------------- MFMA flash attention (r13 form) ----------------
__global__ __launch_bounds__(256) void attn_k(const ushort* __restrict__ qkv, ushort* __restrict__ ctx)
{
  const int qb = blockIdx.x, bh = blockIdx.y;
  const int b = bh/12, h = bh%12;
  const int tid = threadIdx.x;
  const int lane = tid & 63, w = tid >> 6;
  const int fr = lane & 15, fq = lane >> 4;
  __shared__ __align__(16) ushort Ks[4096];
  __shared__ __align__(16) ushort Vts[4096];
  __shared__ __align__(16) ushort Ps[4096];
  const size_t tokq = (size_t)b*1024 + (size_t)qb*64;

  bf16x8 qf[2];
  {
    const ushort* qp = qkv + (tokq + w*16 + fr)*2304 + h*64 + fq*8;
    qf[0] = *(const bf16x8*)(qp);
    qf[1] = *(const bf16x8*)(qp + 32);
  }
  f32x4 o[4];
  #pragma unroll
  for (int nt=0;nt<4;nt++) o[nt] = (f32x4){0.f,0.f,0.f,0.f};
  float m[4] = {-1e30f,-1e30f,-1e30f,-1e30f};
  float l[4] = {0.f,0.f,0.f,0.f};

  const int skr = tid>>3, skc = (tid&7)*8;
  const int svd = (tid&15)*4, svk = (tid>>4)*4;

  for (int kt=0; kt<16; ++kt){
    __syncthreads();
    const size_t tokk = (size_t)b*1024 + (size_t)kt*64;
    #pragma unroll
    for (int pp=0;pp<2;pp++){
      int row = skr + pp*32;
      uint4 kq = *(const uint4*)(qkv + (tokk+row)*2304 + 768 + h*64 + skc);
      *(uint4*)&Ks[row*64 + (skc ^ ((row&7)<<3))] = kq;
    }
    {
      union { ushort4 v4[4]; ushort s[16]; } tv;
      #pragma unroll
      for (int i=0;i<4;i++)
        tv.v4[i] = *(const ushort4*)(qkv + (tokk+svk+i)*2304 + 1536 + h*64 + svd);
      #pragma unroll
      for (int j=0;j<4;j++){
        ushort4 tj; tj.x=tv.s[j]; tj.y=tv.s[4+j]; tj.z=tv.s[8+j]; tj.w=tv.s[12+j];
        int dr = svd + j;
        *(ushort4*)&Vts[dr*64 + (svk ^ ((dr&7)<<3))] = tj;
      }
    }
    __syncthreads();
    f32x4 s[4];
    __builtin_amdgcn_s_setprio(1);
    #pragma unroll
    for (int nt=0;nt<4;nt++){
      s[nt] = (f32x4){0.f,0.f,0.f,0.f};
      int kr = nt*16 + fr;
      const ushort* kb = &Ks[kr*64];
      int sw = (kr&7)<<3;
      bf16x8 k0 = *(const bf16x8*)&kb[(fq*8) ^ sw];
      bf16x8 k1 = *(const bf16x8*)&kb[(fq*8+32) ^ sw];
      s[nt] = __builtin_amdgcn_mfma_f32_16x16x32_bf16(qf[0], k0, s[nt], 0,0,0);
      s[nt] = __builtin_amdgcn_mfma_f32_16x16x32_bf16(qf[1], k1, s[nt], 0,0,0);
    }
    __builtin_amdgcn_s_setprio(0);
    float a_[4], pr[4][4];
    #pragma unroll
    for (int j=0;j<4;j++){
      float mx = fmaxf(fmaxf(s[0][j],s[1][j]), fmaxf(s[2][j],s[3][j])) * 0.125f;
      mx = fmaxf(mx, __shfl_xor(mx,1));
      mx = fmaxf(mx, __shfl_xor(mx,2));
      mx = fmaxf(mx, __shfl_xor(mx,4));
      mx = fmaxf(mx, __shfl_xor(mx,8));
      float mn = fmaxf(m[j], mx);
      float aa = __expf(m[j] - mn);
      m[j] = mn; a_[j] = aa;
      float ss = 0.f;
      #pragma unroll
      for (int nt=0;nt<4;nt++){
        float pv = __expf(s[nt][j]*0.125f - mn);
        pr[nt][j] = pv; ss += pv;
      }
      ss += __shfl_xor(ss,1);
      ss += __shfl_xor(ss,2);
      ss += __shfl_xor(ss,4);
      ss += __shfl_xor(ss,8);
      l[j] = l[j]*aa + ss;
    }
    #pragma unroll
    for (int nt=0;nt<4;nt++){
      #pragma unroll
      for (int j=0;j<4;j++){
        int row = fq*4 + j;
        Ps[w*1024 + row*64 + ((nt*16+fr) ^ ((row&7)<<3))] = f2b(pr[nt][j]);
        o[nt][j] *= a_[j];
      }
    }
    __builtin_amdgcn_s_setprio(1);
    #pragma unroll
    for (int ks=0; ks<2; ++ks){
      int kvo = ks*32 + fq*8;
      bf16x8 pf = *(const bf16x8*)&Ps[w*1024 + fr*64 + (kvo ^ ((fr&7)<<3))];
      #pragma unroll
      for (int nt=0;nt<4;nt++){
        int dr = nt*16 + fr;
        bf16x8 vf = *(const bf16x8*)&Vts[dr*64 + (kvo ^ ((dr&7)<<3))];
        o[nt] = __builtin_amdgcn_mfma_f32_16x16x32_bf16(pf, vf, o[nt], 0,0,0);
      }
    }
    __builtin_amdgcn_s_setprio(0);
  }
  float inv[4];
  #pragma unroll
  for (int j=0;j<4;j++) inv[j] = 1.f/l[j];
  ushort* cp = ctx + (tokq + w*16)*768 + h*64;
  #pragma unroll
  for (int nt=0;nt<4;nt++){
    #pragma unroll
    for (int j=0;j<4;j++){
      cp[(size_t)(fq*4+j)*768 + nt*16 + fr] = f2b(o[nt][j]*inv[j]);
    }
  }
}

// ---------------- workspace layout ----------------
#define OFF_POOL   0u
#define OFF_Z      108527616u
#define OFF_COEF   121110528u
#define OFF_LISTS  121372672u
#define OFF_INV    121536512u
#define OFF_CNT    121700352u
#define OFF_B1P    121700608u
#define OFF_QKV    121835776u
#define OFF_CTX    159584512u
#define OFF_XN1    172167424u
#define WS_GROUPED 222499072u
#define OFF_OUTC   222499072u
#define WS_BIG     247664896u

extern "C" void kernel_launch(void* const* d_in, const int* in_sizes, int n_in,
                              void* d_out, int out_size, void* d_ws, size_t ws_size,
                              hipStream_t stream)
{
  const float* x    = (const float*)d_in[0];
  const int*   mt   = (const int*)d_in[1];
  const float* n1g  = (const float*)d_in[2];
  const float* n1b  = (const float*)d_in[3];
  const float* n2g  = (const float*)d_in[4];
  const float* n2b  = (const float*)d_in[5];
  const float* wqkv = (const float*)d_in[6];
  const float* bqkv = (const float*)d_in[7];
  const float* wo   = (const float*)d_in[8];
  const float* bo   = (const float*)d_in[9];
  const float* rw   = (const float*)d_in[10];
  const float* rb   = (const float*)d_in[11];
  const float* slg  = (const float*)d_in[12];
  const float* slb  = (const float*)d_in[13];
  const float* sw1  = (const float*)d_in[14];
  const float* sb1  = (const float*)d_in[15];
  const float* sw2  = (const float*)d_in[16];
  const float* sb2  = (const float*)d_in[17];
  const float* glg  = (const float*)d_in[18];
  const float* glb  = (const float*)d_in[19];
  const float* gw1  = (const float*)d_in[20];
  const float* gb1  = (const float*)d_in[21];
  const float* gw2  = (const float*)d_in[22];
  const float* gb2  = (const float*)d_in[23];
  float* out = (float*)d_out;
  char* ws = (char*)d_ws;

  ushort* pool  = (ushort*)(ws + OFF_POOL);
  ushort* z     = (ushort*)(ws + OFF_Z);
  float*  coef  = (float*) (ws + OFF_COEF);
  ushort* lists = (ushort*)(ws + OFF_LISTS);
  ushort* invp  = (ushort*)(ws + OFF_INV);
  int*    cnt   = (int*)   (ws + OFF_CNT);
  float*  b1p   = (float*) (ws + OFF_B1P);
  ushort* qkv   = (ushort*)(ws + OFF_QKV);
  ushort* ctx   = (ushort*)(ws + OFF_CTX);
  ushort* xn1   = (ushort*)(ws + OFF_XN1);
  ushort* hidden= (ushort*)(ws + OFF_QKV);
  ushort* outC  = (ushort*)(ws + OFF_OUTC);

  ushort* pWqkv = pool + 0;
  ushort* pWo   = pool + 1769472;
  ushort* pSw1  = pool + 2359296;
  ushort* pSw2  = pool + 9437184;
  ushort* pGw1  = pool + 16515072;
  ushort* pGw2  = pool + 35389440;

  const int tier = (ws_size >= (size_t)WS_BIG) ? 2 : ((ws_size >= (size_t)WS_GROUPED) ? 1 : 0);

  conv_w<<<52992, 256, 0, stream>>>(wqkv, wo, sw1, sw2, gw1, gw2, slg, glg, pool);
  b1fold_k<<<8448, 256, 0, stream>>>(sw1, gw1, sb1, gb1, slb, glb, b1p);
  ln1_k<<<2048, 256, 0, stream>>>(x, n1g, n1b, xn1);
  { GemmArgs a{}; a.A=xn1; a.B=pWqkv; a.bias=bqkv; a.outBF=qkv; a.K=768; a.ldc=2304;
    gemm_k<<<dim3(64,18),256,0,stream>>>(a); }
  attn_k<<<dim3(16,96),256,0,stream>>>(qkv, ctx);

  FArgs fa{};
  fa.z=z; fa.hidden=hidden; fa.ctx=ctx; fa.wo=pWo; fa.out=out; fa.outC=outC;
  fa.xres=x; fa.bo=bo;
  fa.lists=lists; fa.inv=invp; fa.cnt=cnt; fa.coef=coef;
  fa.sw1=pSw1; fa.gw1=pGw1; fa.sw2=pSw2; fa.gw2=pGw2;
  fa.b1p=b1p; fa.sb2=sb2; fa.gb2=gb2;

  // out-proj with fused residual+bias: dense 2D grid
  { FArgs a = fa; a.jobBase = -1; a.compact = 0; a.mode = 0;
    ffn2_k<<<dim3(128,6),256,0,stream>>>(a); }

  lnr_k<<<2048,256,0,stream>>>(out, n2g, n2b, rw, rb, z, coef);
  build_lists<<<10,256,0,stream>>>(mt, coef, lists, invp, cnt);

  if (tier==2){
    { FArgs a = fa; a.jobBase = 0; a.compact = 1; a.mode = 1;
      a.npanels = 36; ffn1_k<<<2560,512,0,stream>>>(a);
      a.npanels = 18; a.kpx = 3; ffn2_k<<<3072,256,0,stream>>>(a); }
    gather_k<<<2048,256,0,stream>>>(coef, mt, invp, cnt, outC, out, 0);
    { FArgs a = fa; a.jobBase = 3; a.compact = 1; a.mode = 1;
      a.npanels = 96; ffn1_k<<<6144,512,0,stream>>>(a);
      a.npanels = 48; a.kpx = 6; ffn2_k<<<6144,256,0,stream>>>(a); }
    gather_k<<<2048,256,0,stream>>>(coef, mt, invp, cnt, outC, out, 1);
  } else if (tier==1){
    { FArgs a = fa; a.jobBase = 0; a.compact = 1; a.mode = 0;
      a.npanels = 36; ffn1_k<<<2560,512,0,stream>>>(a);
      a.npanels = 18; a.kpx = 3; ffn2_k<<<3072,256,0,stream>>>(a); }
    { FArgs a = fa; a.jobBase = 3; a.compact = 1; a.mode = 0;
      a.npanels = 96; ffn1_k<<<6144,512,0,stream>>>(a);
      a.npanels = 48; a.kpx = 6; ffn2_k<<<6144,256,0,stream>>>(a); }
  } else {
    for (int j=0;j<11;j++){
      FArgs a = fa; a.jobBase = j; a.compact = 0; a.mode = 0;
      a.npanels = 12; ffn1_k<<<1024,512,0,stream>>>(a);
      a.npanels = 6;  a.kpx = 1; ffn2_k<<<1024,256,0,stream>>>(a);
    }
  }
}

// Round 20
// 950.410 us; speedup vs baseline: 1.1644x; 1.0026x over previous
//
#include <hip/hip_runtime.h>
#include <cstdint>

#define NTOK 8192
#define EDIM 768
#define FDIM 3072

using bf16x8 = __attribute__((ext_vector_type(8))) __bf16;
using f32x4  = __attribute__((ext_vector_type(4))) float;

__device__ __forceinline__ float b2f(ushort u){ union{uint32_t i; float f;} v; v.i = ((uint32_t)u)<<16; return v.f; }
__device__ __forceinline__ ushort f2b(float f){ union{float f; uint32_t i;} v; v.f=f; uint32_t r = v.i + 0x7fffu + ((v.i>>16)&1u); return (ushort)(r>>16); }
__device__ __forceinline__ float gelu_f(float v){
  float c = v*(1.5957691216f + 0.0713548162726f*v*v);
  return v / (1.f + __expf(-c));
}
__device__ __forceinline__ void gload16(const ushort* g, ushort* l){
  __builtin_amdgcn_global_load_lds((const __attribute__((address_space(1))) void*)g,
                                   (__attribute__((address_space(3))) void*)l, 16, 0, 0);
}

// ---------------- fused preprocessing: weight conv + b1 fold + LN1 (independent jobs) ----------------
struct PreArgs {
  const float *wqkv,*wo,*sw1,*sw2,*gw1,*gw2,*slg,*glg;
  const float *sb1,*gb1,*slb,*glb;
  const float *x,*n1g,*n1b;
  ushort* pool; float* b1p; ushort* xn1;
};

__global__ __launch_bounds__(256) void pre_k(PreArgs a)
{
  const int bid = blockIdx.x;
  if (bid < 52992){
    // weight fp32 -> bf16 pool (LN gains folded into W1 rows)
    size_t idx4 = (size_t)bid*256 + threadIdx.x;
    size_t e = idx4*4;
    const float* src; size_t base; int region;
    if      (e <  1769472u){src=a.wqkv;base=0;        region=0;}
    else if (e <  2359296u){src=a.wo;  base=1769472u; region=1;}
    else if (e <  9437184u){src=a.sw1; base=2359296u; region=2;}
    else if (e < 16515072u){src=a.sw2; base=9437184u; region=3;}
    else if (e < 35389440u){src=a.gw1; base=16515072u;region=4;}
    else                   {src=a.gw2; base=35389440u;region=5;}
    size_t within = e - base;
    f32x4 f = *(const f32x4*)(src + within);
    if (region==2){
      int ex = (int)(within/2359296u); int col = (int)(within%768u);
      f32x4 g = *(const f32x4*)(a.slg + ex*768 + col);
      f[0]*=g[0]; f[1]*=g[1]; f[2]*=g[2]; f[3]*=g[3];
    } else if (region==4){
      int ex = (int)(within/2359296u); int col = (int)(within%768u);
      f32x4 g = *(const f32x4*)(a.glg + ex*768 + col);
      f[0]*=g[0]; f[1]*=g[1]; f[2]*=g[2]; f[3]*=g[3];
    }
    ushort4 u; u.x=f2b(f[0]); u.y=f2b(f[1]); u.z=f2b(f[2]); u.w=f2b(f[3]);
    *(ushort4*)(a.pool+e) = u;
  } else if (bid < 61440){
    // b1p[j] = b1[j] + W1row . lb
    int j = (bid-52992)*4 + ((int)threadIdx.x>>6);
    int lane = threadIdx.x & 63;
    int je = j / FDIM, f = j % FDIM;
    const float* wrow = (je<3) ? a.sw1 + ((size_t)je*FDIM + f)*EDIM : a.gw1 + ((size_t)(je-3)*FDIM + f)*EDIM;
    const float* lb   = (je<3) ? a.slb + (size_t)je*EDIM : a.glb + (size_t)(je-3)*EDIM;
    float s = 0.f;
    #pragma unroll
    for (int i=0;i<12;i++){ int d = lane + 64*i; s += wrow[d]*lb[d]; }
    #pragma unroll
    for (int o=32;o>0;o>>=1) s += __shfl_xor(s,o);
    if (lane==0){
      float base = (je<3) ? a.sb1[je*FDIM+f] : a.gb1[(je-3)*FDIM+f];
      a.b1p[j] = base + s;
    }
  } else {
    // LN1(x) -> xn1 (bf16)
    int w = (bid-61440)*4 + ((int)threadIdx.x>>6);
    int lane = threadIdx.x & 63;
    const float* xr = a.x + (size_t)w*EDIM;
    float v[12]; float s=0.f, s2=0.f;
    #pragma unroll
    for (int i=0;i<12;i++){ v[i]=xr[lane+64*i]; s+=v[i]; s2+=v[i]*v[i]; }
    #pragma unroll
    for (int o=32;o>0;o>>=1){ s += __shfl_xor(s,o); s2 += __shfl_xor(s2,o); }
    float mu = s*(1.f/768.f);
    float rs = rsqrtf(s2*(1.f/768.f) - mu*mu + 1e-5f);
    ushort* op = a.xn1 + (size_t)w*EDIM;
    #pragma unroll
    for (int i=0;i<12;i++){ int d=lane+64*i; op[d] = f2b((v[i]-mu)*rs*a.n1g[d] + a.n1b[d]); }
  }
}

__global__ __launch_bounds__(256) void lnr_k(const float* __restrict__ x1, const float* __restrict__ g2,
                                             const float* __restrict__ b2, const float* __restrict__ rw,
                                             const float* __restrict__ rbv,
                                             ushort* __restrict__ z, float* __restrict__ coef)
{
  int w = blockIdx.x*4 + (threadIdx.x>>6);
  int lane = threadIdx.x & 63;
  const float* xr = x1 + (size_t)w*EDIM;
  float v[12]; float s=0.f, s2=0.f;
  #pragma unroll
  for (int i=0;i<12;i++){ v[i]=xr[lane+64*i]; s+=v[i]; s2+=v[i]*v[i]; }
  #pragma unroll
  for (int o=32;o>0;o>>=1){ s += __shfl_xor(s,o); s2 += __shfl_xor(s2,o); }
  float mu = s*(1.f/768.f);
  float rs = rsqrtf(s2*(1.f/768.f) - mu*mu + 1e-5f);
  float xn[12]; s=0.f; s2=0.f;
  #pragma unroll
  for (int i=0;i<12;i++){ int d=lane+64*i; xn[i]=(v[i]-mu)*rs*g2[d]+b2[d]; s+=xn[i]; s2+=xn[i]*xn[i]; }
  float pl[8] = {0.f,0.f,0.f,0.f,0.f,0.f,0.f,0.f};
  #pragma unroll
  for (int i=0;i<12;i++){
    int d=lane+64*i; float xv=xn[i];
    #pragma unroll
    for (int e=0;e<8;e++) pl[e] += xv * rw[e*EDIM + d];
  }
  #pragma unroll
  for (int o=32;o>0;o>>=1){ s += __shfl_xor(s,o); s2 += __shfl_xor(s2,o); }
  float mu2 = s*(1.f/768.f);
  float rs2 = rsqrtf(s2*(1.f/768.f) - mu2*mu2 + 1e-5f);
  ushort* op = z + (size_t)w*EDIM;
  #pragma unroll
  for (int i=0;i<12;i++){ int d=lane+64*i; op[d] = f2b((xn[i]-mu2)*rs2); }
  #pragma unroll
  for (int e=0;e<8;e++){
    #pragma unroll
    for (int o=32;o>0;o>>=1) pl[e] += __shfl_xor(pl[e], o);
  }
  float lgt[8]; float mx = -1e30f;
  #pragma unroll
  for (int e=0;e<8;e++){ lgt[e]=pl[e]+rbv[e]; mx = fmaxf(mx, lgt[e]); }
  float p[8]; float den=0.f;
  #pragma unroll
  for (int e=0;e<8;e++){ p[e]=__expf(lgt[e]-mx); den+=p[e]; }
  float inv = 1.f/den;
  #pragma unroll
  for (int e=0;e<8;e++) p[e]*=inv;
  int i1=0;
  #pragma unroll
  for (int e=1;e<8;e++) if (p[e]>p[i1]) i1=e;
  int i2=(i1==0)?1:0;
  #pragma unroll
  for (int e=0;e<8;e++){ if (e==i1) continue; if (p[e]>p[i2]) i2=e; }
  float w1 = 1.f/(1.f+__expf(p[i2]-p[i1]));
  float w2 = 1.f - w1;
  if (lane < 8){
    float c = (lane==i1)? w1 : ((lane==i2)? w2 : 0.f);
    coef[(size_t)w*8 + lane] = c;
  }
}

__global__ __launch_bounds__(256) void build_lists(const int* __restrict__ mt, const float* __restrict__ coef,
                                                   ushort* __restrict__ lists, ushort* __restrict__ inv,
                                                   int* __restrict__ cnt)
{
  const int job = blockIdx.x;
  ushort* list = lists + (size_t)job*NTOK;
  __shared__ int wsum[4];
  int base = 0;
  const int lane = threadIdx.x & 63, wv = threadIdx.x >> 6;
  for (int c0=0; c0<NTOK; c0+=256){
    int t = c0 + threadIdx.x;
    bool flag;
    if (job==0)      flag = (mt[t]==0);
    else if (job==1) flag = (mt[t]==1);
    else             flag = (coef[(size_t)t*8 + (job-2)] != 0.0f);
    unsigned long long bal = __ballot(flag);
    int pre = __popcll(bal & ((1ull<<lane)-1ull));
    if (lane==0) wsum[wv] = __popcll(bal);
    __syncthreads();
    int off = base + pre;
    for (int k=0;k<wv;k++) off += wsum[k];
    int tot = wsum[0]+wsum[1]+wsum[2]+wsum[3];
    if (flag){ list[off] = (ushort)t; inv[(size_t)job*NTOK + t] = (ushort)off; }
    base += tot;
    __syncthreads();
  }
  if (threadIdx.x==0){ cnt[job+1] = base; if (job==0) cnt[0] = NTOK; }
}

__global__ __launch_bounds__(256) void gather_k(const float* __restrict__ coef, const int* __restrict__ mt,
                                                const ushort* __restrict__ inv, const int* __restrict__ cnt,
                                                const ushort* __restrict__ outC, float* __restrict__ out,
                                                int phase)
{
  int t = blockIdx.x*4 + (threadIdx.x>>6);
  int lane = threadIdx.x & 63;
  int r0, r1; float c0=1.f, c1=1.f;
  if (phase==0){
    r0 = t;
    int m = mt[t];
    r1 = NTOK + (m ? cnt[1] : 0) + (int)inv[(size_t)m*NTOK + t];
  } else {
    int found=0; int rr[2]={0,0}; float cc[2]={0.f,0.f}; int base=0;
    #pragma unroll
    for (int e=0;e<8;e++){
      float ce = coef[(size_t)t*8+e];
      if (ce != 0.f && found<2){ rr[found]=base+(int)inv[(size_t)(2+e)*NTOK + t]; cc[found]=ce; found++; }
      base += cnt[3+e];
    }
    r0=rr[0]; r1=rr[1]; c0=cc[0]; c1=cc[1];
  }
  const ushort* pa = outC + (size_t)r0*EDIM;
  const ushort* pb = outC + (size_t)r1*EDIM;
  float* po = out + (size_t)t*EDIM;
  #pragma unroll
  for (int i=0;i<3;i++){
    int d = lane*4 + 256*i;
    ushort4 ua = *(const ushort4*)(pa+d);
    ushort4 ub = *(const ushort4*)(pb+d);
    f32x4 o = *(f32x4*)(po+d);
    o[0] += c0*b2f(ua.x) + c1*b2f(ub.x);
    o[1] += c0*b2f(ua.y) + c1*b2f(ub.y);
    o[2] += c0*b2f(ua.z) + c1*b2f(ub.z);
    o[3] += c0*b2f(ua.w) + c1*b2f(ub.w);
    *(f32x4*)(po+d) = o;
  }
}

// ---------------- dense MFMA GEMM (QKV), 128x128, single-buffer gload ----------------
struct GemmArgs {
  const ushort* A; const ushort* B;
  const float* bias;
  ushort* outBF;
  int K, ldc;
};

__global__ __launch_bounds__(256) void gemm_k(GemmArgs g)
{
  const int mb = blockIdx.x, nb = blockIdx.y;
  __shared__ __align__(1024) ushort As[128*32];
  __shared__ __align__(1024) ushort Bs[128*32];
  const int tid = threadIdx.x;
  const int lane = tid & 63, w = tid >> 6;
  const int seg = lane & 3;
  const int lrow = w*16 + (lane>>2);
  const int p = (lane>>3)&3;
  ushort* ldsA0 = As + (size_t)w*512;
  ushort* ldsA1 = As + (size_t)(w+4)*512;
  ushort* ldsB0 = Bs + (size_t)w*512;
  ushort* ldsB1 = Bs + (size_t)(w+4)*512;
  const int KK = g.K;
  const ushort* pA0 = g.A + (size_t)(mb*128 + lrow)*KK + (seg^p)*8;
  const ushort* pA1 = pA0 + (size_t)64*KK;
  const ushort* pB0 = g.B + (size_t)(nb*128 + lrow)*KK + (seg^p)*8;
  const ushort* pB1 = pB0 + (size_t)64*KK;
  const int nst = KK >> 5;
  f32x4 acc[4][4];
  #pragma unroll
  for (int m=0;m<4;m++)
    #pragma unroll
    for (int n=0;n<4;n++) acc[m][n] = (f32x4){0.f,0.f,0.f,0.f};
  const int fr = lane & 15, fq = lane >> 4;
  const int pr = (fr>>1)&3;
  const int so = (fq^pr)*8;
  const int rb_ = (w>>1)*64, cb_ = (w&1)*64;
  for (int kt=0; kt<nst; ++kt){
    __syncthreads();
    gload16(pA0, ldsA0); gload16(pA1, ldsA1);
    gload16(pB0, ldsB0); gload16(pB1, ldsB1);
    pA0 += 32; pA1 += 32; pB0 += 32; pB1 += 32;
    __syncthreads();
    bf16x8 af[4], bfr[4];
    #pragma unroll
    for (int m=0;m<4;m++) af[m]  = *(const bf16x8*)&As[(rb_ + m*16 + fr)*32 + so];
    #pragma unroll
    for (int n=0;n<4;n++) bfr[n] = *(const bf16x8*)&Bs[(cb_ + n*16 + fr)*32 + so];
    #pragma unroll
    for (int m=0;m<4;m++)
      #pragma unroll
      for (int n=0;n<4;n++)
        acc[m][n] = __builtin_amdgcn_mfma_f32_16x16x32_bf16(af[m], bfr[n], acc[m][n], 0, 0, 0);
  }
  #pragma unroll
  for (int m=0;m<4;m++){
    #pragma unroll
    for (int j=0;j<4;j++){
      const int row = mb*128 + rb_ + m*16 + fq*4 + j;
      #pragma unroll
      for (int n=0;n<4;n++){
        const int col = nb*128 + cb_ + n*16 + fr;
        g.outBF[(size_t)row*g.ldc + col] = f2b(acc[m][n][j] + g.bias[col]);
      }
    }
  }
}

// ---------------- grouped expert FFN kernels ----------------
struct FArgs {
  const ushort* z; ushort* hidden; const ushort* ctx; const ushort* wo;
  float* out; ushort* outC;
  const float* xres; const float* bo;
  const ushort* lists; const ushort* inv; const int* cnt; const float* coef;
  const ushort* sw1; const ushort* gw1; const ushort* sw2; const ushort* gw2;
  const float* b1p; const float* sb2; const float* gb2;
  int jobBase; int compact; int mode; int npanels; int kpx;
};

__device__ __forceinline__ size_t job_hoff(const FArgs& a, int job){
  size_t h = 0;
  if (a.compact){
    if (job==1) h = NTOK;
    else if (job==2) h = NTOK + (size_t)a.cnt[1];
    else if (job>=3){ for (int k=3;k<job;k++) h += (size_t)a.cnt[k]; }
  }
  return h;
}

// FFN1: 128x256 tile, 512 threads (8 waves, 2x4), BK=64, single-buffer gload.
__global__ __launch_bounds__(512) void ffn1_k(FArgs a)
{
  const int bid = blockIdx.x;
  const int xcd = bid & 7;
  const int r = bid >> 3;
  const int pslot = xcd + 8*(r >> 6);
  const int mb = r & 63;
  if (pslot >= a.npanels) return;
  const int jz = pslot / 12;
  const int nb = pslot % 12;
  const int job = a.jobBase + jz;
  const int cntj = (job==0) ? NTOK : a.cnt[job];
  if (mb*128 >= cntj) return;
  const ushort* list = (job==0) ? nullptr : a.lists + (size_t)(job-1)*NTOK;
  const ushort* B = (job<3) ? a.sw1+(size_t)job*FDIM*EDIM : a.gw1+(size_t)(job-3)*FDIM*EDIM;
  const float* bias = a.b1p + (size_t)job*FDIM;
  const size_t hoff = job_hoff(a, job);
  __shared__ __align__(1024) ushort As[128*64];
  __shared__ __align__(1024) ushort Bs[256*64];
  const int tid = threadIdx.x;
  const int lane = tid & 63, w = tid >> 6;
  const int rl = lane >> 3, ch = lane & 7;
  const int chp = ch ^ rl;
  const int arow0 = w*8 + rl, arow1 = 64 + w*8 + rl;
  const int tA0 = list ? (int)list[min(mb*128+arow0, cntj-1)] : min(mb*128+arow0, cntj-1);
  const int tA1 = list ? (int)list[min(mb*128+arow1, cntj-1)] : min(mb*128+arow1, cntj-1);
  const ushort* pA0 = a.z + (size_t)tA0*EDIM + chp*8;
  const ushort* pA1 = a.z + (size_t)tA1*EDIM + chp*8;
  ushort* dA0 = As + (size_t)w*512;
  ushort* dA1 = As + 4096 + (size_t)w*512;
  const ushort* pB0 = B + (size_t)(nb*256 +       w*8 + rl)*EDIM + chp*8;
  const ushort* pB1 = B + (size_t)(nb*256 +  64 + w*8 + rl)*EDIM + chp*8;
  const ushort* pB2 = B + (size_t)(nb*256 + 128 + w*8 + rl)*EDIM + chp*8;
  const ushort* pB3 = B + (size_t)(nb*256 + 192 + w*8 + rl)*EDIM + chp*8;
  ushort* dB0 = Bs + (size_t)w*512;
  ushort* dB1 = Bs +  4096 + (size_t)w*512;
  ushort* dB2 = Bs +  8192 + (size_t)w*512;
  ushort* dB3 = Bs + 12288 + (size_t)w*512;
  f32x4 acc[4][4];
  #pragma unroll
  for (int m=0;m<4;m++)
    #pragma unroll
    for (int n=0;n<4;n++) acc[m][n] = (f32x4){0.f,0.f,0.f,0.f};
  const int fr = lane & 15, fq = lane >> 4;
  const int rb_ = (w>>2)*64;
  const int cb_ = (w&3)*64;
  for (int kt=0; kt<12; ++kt){
    __syncthreads();
    gload16(pA0, dA0); gload16(pA1, dA1);
    gload16(pB0, dB0); gload16(pB1, dB1); gload16(pB2, dB2); gload16(pB3, dB3);
    pA0 += 64; pA1 += 64; pB0 += 64; pB1 += 64; pB2 += 64; pB3 += 64;
    __syncthreads();
    #pragma unroll
    for (int ks=0; ks<2; ++ks){
      const int c = fq + 4*ks;
      bf16x8 af[4], bfr[4];
      #pragma unroll
      for (int m=0;m<4;m++){ int rr = rb_ + m*16 + fr; af[m]  = *(const bf16x8*)&As[rr*64 + ((c^(rr&7))<<3)]; }
      #pragma unroll
      for (int n=0;n<4;n++){ int rr = cb_ + n*16 + fr; bfr[n] = *(const bf16x8*)&Bs[rr*64 + ((c^(rr&7))<<3)]; }
      #pragma unroll
      for (int m=0;m<4;m++)
        #pragma unroll
        for (int n=0;n<4;n++)
          acc[m][n] = __builtin_amdgcn_mfma_f32_16x16x32_bf16(af[m], bfr[n], acc[m][n], 0, 0, 0);
    }
  }
  #pragma unroll
  for (int m=0;m<4;m++){
    #pragma unroll
    for (int j=0;j<4;j++){
      const int row = mb*128 + rb_ + m*16 + fq*4 + j;
      if (row < cntj){
        #pragma unroll
        for (int n=0;n<4;n++){
          const int col = nb*256 + cb_ + n*16 + fr;
          a.hidden[(hoff+row)*FDIM + col] = f2b(gelu_f(acc[m][n][j] + bias[col]));
        }
      }
    }
  }
}

// FFN2 / out-proj: 64x128 tile, BK=64, single-buffer gload.
__global__ __launch_bounds__(256) void ffn2_k(FArgs a)
{
  const bool op = (a.jobBase < 0);
  int mb, nb, job;
  if (op){
    mb = blockIdx.x; nb = blockIdx.y; job = -1;
  } else {
    const int bid = blockIdx.x;
    const int xcd = bid & 7;
    const int r = bid >> 3;
    const int k = r % a.kpx;
    mb = r / a.kpx;
    const int pslot = xcd + 8*k;
    if (pslot >= a.npanels) return;
    job = a.jobBase + pslot / 6;
    nb = pslot % 6;
  }
  const int cntj = op ? NTOK : ((job==0) ? NTOK : a.cnt[job]);
  if (mb*64 >= cntj) return;
  const ushort* list = (op || job==0) ? nullptr : a.lists + (size_t)(job-1)*NTOK;
  const ushort* Abase; int lda; const ushort* B; const float* bias = nullptr;
  const float* coefp = nullptr; int eidx = 0;
  if (op){ Abase = a.ctx; lda = EDIM; B = a.wo; }
  else {
    lda = FDIM;
    Abase = a.hidden + job_hoff(a, job)*FDIM;
    if (job<3){ B=a.sw2+(size_t)job*(size_t)EDIM*FDIM; bias=a.sb2+(size_t)job*EDIM; }
    else { eidx=job-3; B=a.gw2+(size_t)eidx*(size_t)EDIM*FDIM; bias=a.gb2+(size_t)eidx*EDIM; coefp=a.coef; }
  }
  const int nst = lda >> 6;
  __shared__ __align__(1024) ushort As[64*64];
  __shared__ __align__(1024) ushort Bs[128*64];
  const int tid = threadIdx.x;
  const int lane = tid & 63, w = tid >> 6;
  const int rl = lane >> 3, ch = lane & 7;
  const int chp = ch ^ rl;
  const int ar0 = w*8 + rl, ar1 = 32 + w*8 + rl;
  const ushort* pA0 = Abase + (size_t)min(mb*64+ar0, cntj-1)*lda + chp*8;
  const ushort* pA1 = Abase + (size_t)min(mb*64+ar1, cntj-1)*lda + chp*8;
  ushort* dA0 = As + (size_t)w*512;
  ushort* dA1 = As + 2048 + (size_t)w*512;
  const ushort* pB0 = B + (size_t)(nb*128 +      w*8 + rl)*lda + chp*8;
  const ushort* pB1 = B + (size_t)(nb*128 + 32 + w*8 + rl)*lda + chp*8;
  const ushort* pB2 = B + (size_t)(nb*128 + 64 + w*8 + rl)*lda + chp*8;
  const ushort* pB3 = B + (size_t)(nb*128 + 96 + w*8 + rl)*lda + chp*8;
  ushort* dB0 = Bs + (size_t)w*512;
  ushort* dB1 = Bs + 2048 + (size_t)w*512;
  ushort* dB2 = Bs + 4096 + (size_t)w*512;
  ushort* dB3 = Bs + 6144 + (size_t)w*512;
  f32x4 acc[4][2];
  #pragma unroll
  for (int m=0;m<4;m++)
    #pragma unroll
    for (int n=0;n<2;n++) acc[m][n] = (f32x4){0.f,0.f,0.f,0.f};
  const int fr = lane & 15, fq = lane >> 4;
  const int cb_ = w*32;
  for (int kt=0; kt<nst; ++kt){
    __syncthreads();
    gload16(pA0, dA0); gload16(pA1, dA1);
    gload16(pB0, dB0); gload16(pB1, dB1); gload16(pB2, dB2); gload16(pB3, dB3);
    pA0 += 64; pA1 += 64; pB0 += 64; pB1 += 64; pB2 += 64; pB3 += 64;
    __syncthreads();
    #pragma unroll
    for (int ks=0; ks<2; ++ks){
      const int c = fq + 4*ks;
      bf16x8 af[4], bfr[2];
      #pragma unroll
      for (int m=0;m<4;m++){ int rr = m*16 + fr;  af[m]  = *(const bf16x8*)&As[rr*64 + ((c^(rr&7))<<3)]; }
      #pragma unroll
      for (int n=0;n<2;n++){ int rr = cb_ + n*16 + fr; bfr[n] = *(const bf16x8*)&Bs[rr*64 + ((c^(rr&7))<<3)]; }
      #pragma unroll
      for (int m=0;m<4;m++)
        #pragma unroll
        for (int n=0;n<2;n++)
          acc[m][n] = __builtin_amdgcn_mfma_f32_16x16x32_bf16(af[m], bfr[n], acc[m][n], 0, 0, 0);
    }
  }
  #pragma unroll
  for (int m=0;m<4;m++){
    #pragma unroll
    for (int j=0;j<4;j++){
      const int row = mb*64 + m*16 + fq*4 + j;
      if (row < cntj){
        #pragma unroll
        for (int n=0;n<2;n++){
          const int col = nb*128 + cb_ + n*16 + fr;
          float v = acc[m][n][j];
          if (op){
            a.out[(size_t)row*EDIM + col] = a.xres[(size_t)row*EDIM + col] + a.bo[col] + v;
          } else if (a.mode==1){
            a.outC[(job_hoff(a,job)+row)*EDIM + col] = f2b(v + bias[col]);
          } else {
            const int tok = list ? (int)list[row] : row;
            const float c = coefp ? coefp[(size_t)tok*8 + eidx] : 1.0f;
            atomicAdd(&a.out[(size_t)tok*EDIM + col], c*(v + bias[col]));
          }
        }
      }
    }
  }
}

// ---------------- MFMA flash attention ----------------
__global__ __launch_bounds__(256) void attn_k(const ushort* __restrict__ qkv, ushort* __restrict__ ctx)
{
  const int qb = blockIdx.x, bh = blockIdx.y;
  const int b = bh/12, h = bh%12;
  const int tid = threadIdx.x;
  const int lane = tid & 63, w = tid >> 6;
  const int fr = lane & 15, fq = lane >> 4;
  __shared__ __align__(16) ushort Ks[4096];
  __shared__ __align__(16) ushort Vts[4096];
  __shared__ __align__(16) ushort Ps[4096];
  const size_t tokq = (size_t)b*1024 + (size_t)qb*64;

  bf16x8 qf[2];
  {
    const ushort* qp = qkv + (tokq + w*16 + fr)*2304 + h*64 + fq*8;
    qf[0] = *(const bf16x8*)(qp);
    qf[1] = *(const bf16x8*)(qp + 32);
  }
  f32x4 o[4];
  #pragma unroll
  for (int nt=0;nt<4;nt++) o[nt] = (f32x4){0.f,0.f,0.f,0.f};
  float m[4] = {-1e30f,-1e30f,-1e30f,-1e30f};
  float l[4] = {0.f,0.f,0.f,0.f};

  const int skr = tid>>3, skc = (tid&7)*8;
  const int svd = (tid&15)*4, svk = (tid>>4)*4;

  for (int kt=0; kt<16; ++kt){
    __syncthreads();
    const size_t tokk = (size_t)b*1024 + (size_t)kt*64;
    #pragma unroll
    for (int pp=0;pp<2;pp++){
      int row = skr + pp*32;
      uint4 kq = *(const uint4*)(qkv + (tokk+row)*2304 + 768 + h*64 + skc);
      *(uint4*)&Ks[row*64 + (skc ^ ((row&7)<<3))] = kq;
    }
    {
      union { ushort4 v4[4]; ushort s[16]; } tv;
      #pragma unroll
      for (int i=0;i<4;i++)
        tv.v4[i] = *(const ushort4*)(qkv + (tokk+svk+i)*2304 + 1536 + h*64 + svd);
      #pragma unroll
      for (int j=0;j<4;j++){
        ushort4 tj; tj.x=tv.s[j]; tj.y=tv.s[4+j]; tj.z=tv.s[8+j]; tj.w=tv.s[12+j];
        int dr = svd + j;
        *(ushort4*)&Vts[dr*64 + (svk ^ ((dr&7)<<3))] = tj;
      }
    }
    __syncthreads();
    f32x4 s[4];
    __builtin_amdgcn_s_setprio(1);
    #pragma unroll
    for (int nt=0;nt<4;nt++){
      s[nt] = (f32x4){0.f,0.f,0.f,0.f};
      int kr = nt*16 + fr;
      const ushort* kb = &Ks[kr*64];
      int sw = (kr&7)<<3;
      bf16x8 k0 = *(const bf16x8*)&kb[(fq*8) ^ sw];
      bf16x8 k1 = *(const bf16x8*)&kb[(fq*8+32) ^ sw];
      s[nt] = __builtin_amdgcn_mfma_f32_16x16x32_bf16(qf[0], k0, s[nt], 0,0,0);
      s[nt] = __builtin_amdgcn_mfma_f32_16x16x32_bf16(qf[1], k1, s[nt], 0,0,0);
    }
    __builtin_amdgcn_s_setprio(0);
    float a_[4], pr[4][4];
    #pragma unroll
    for (int j=0;j<4;j++){
      float mx = fmaxf(fmaxf(s[0][j],s[1][j]), fmaxf(s[2][j],s[3][j])) * 0.125f;
      mx = fmaxf(mx, __shfl_xor(mx,1));
      mx = fmaxf(mx, __shfl_xor(mx,2));
      mx = fmaxf(mx, __shfl_xor(mx,4));
      mx = fmaxf(mx, __shfl_xor(mx,8));
      float mn = fmaxf(m[j], mx);
      float aa = __expf(m[j] - mn);
      m[j] = mn; a_[j] = aa;
      float ss = 0.f;
      #pragma unroll
      for (int nt=0;nt<4;nt++){
        float pv = __expf(s[nt][j]*0.125f - mn);
        pr[nt][j] = pv; ss += pv;
      }
      ss += __shfl_xor(ss,1);
      ss += __shfl_xor(ss,2);
      ss += __shfl_xor(ss,4);
      ss += __shfl_xor(ss,8);
      l[j] = l[j]*aa + ss;
    }
    #pragma unroll
    for (int nt=0;nt<4;nt++){
      #pragma unroll
      for (int j=0;j<4;j++){
        int row = fq*4 + j;
        Ps[w*1024 + row*64 + ((nt*16+fr) ^ ((row&7)<<3))] = f2b(pr[nt][j]);
        o[nt][j] *= a_[j];
      }
    }
    __builtin_amdgcn_s_setprio(1);
    #pragma unroll
    for (int ks=0; ks<2; ++ks){
      int kvo = ks*32 + fq*8;
      bf16x8 pf = *(const bf16x8*)&Ps[w*1024 + fr*64 + (kvo ^ ((fr&7)<<3))];
      #pragma unroll
      for (int nt=0;nt<4;nt++){
        int dr = nt*16 + fr;
        bf16x8 vf = *(const bf16x8*)&Vts[dr*64 + (kvo ^ ((dr&7)<<3))];
        o[nt] = __builtin_amdgcn_mfma_f32_16x16x32_bf16(pf, vf, o[nt], 0,0,0);
      }
    }
    __builtin_amdgcn_s_setprio(0);
  }
  float inv[4];
  #pragma unroll
  for (int j=0;j<4;j++) inv[j] = 1.f/l[j];
  ushort* cp = ctx + (tokq + w*16)*768 + h*64;
  #pragma unroll
  for (int nt=0;nt<4;nt++){
    #pragma unroll
    for (int j=0;j<4;j++){
      cp[(size_t)(fq*4+j)*768 + nt*16 + fr] = f2b(o[nt][j]*inv[j]);
    }
  }
}

// ---------------- workspace layout ----------------
#define OFF_POOL   0u
#define OFF_Z      108527616u
#define OFF_COEF   121110528u
#define OFF_LISTS  121372672u
#define OFF_INV    121536512u
#define OFF_CNT    121700352u
#define OFF_B1P    121700608u
#define OFF_QKV    121835776u
#define OFF_CTX    159584512u
#define OFF_XN1    172167424u
#define WS_GROUPED 222499072u
#define OFF_OUTC   222499072u
#define WS_BIG     247664896u

extern "C" void kernel_launch(void* const* d_in, const int* in_sizes, int n_in,
                              void* d_out, int out_size, void* d_ws, size_t ws_size,
                              hipStream_t stream)
{
  const float* x    = (const float*)d_in[0];
  const int*   mt   = (const int*)d_in[1];
  const float* n1g  = (const float*)d_in[2];
  const float* n1b  = (const float*)d_in[3];
  const float* n2g  = (const float*)d_in[4];
  const float* n2b  = (const float*)d_in[5];
  const float* wqkv = (const float*)d_in[6];
  const float* bqkv = (const float*)d_in[7];
  const float* wo   = (const float*)d_in[8];
  const float* bo   = (const float*)d_in[9];
  const float* rw   = (const float*)d_in[10];
  const float* rb   = (const float*)d_in[11];
  const float* slg  = (const float*)d_in[12];
  const float* slb  = (const float*)d_in[13];
  const float* sw1  = (const float*)d_in[14];
  const float* sb1  = (const float*)d_in[15];
  const float* sw2  = (const float*)d_in[16];
  const float* sb2  = (const float*)d_in[17];
  const float* glg  = (const float*)d_in[18];
  const float* glb  = (const float*)d_in[19];
  const float* gw1  = (const float*)d_in[20];
  const float* gb1  = (const float*)d_in[21];
  const float* gw2  = (const float*)d_in[22];
  const float* gb2  = (const float*)d_in[23];
  float* out = (float*)d_out;
  char* ws = (char*)d_ws;

  ushort* pool  = (ushort*)(ws + OFF_POOL);
  ushort* z     = (ushort*)(ws + OFF_Z);
  float*  coef  = (float*) (ws + OFF_COEF);
  ushort* lists = (ushort*)(ws + OFF_LISTS);
  ushort* invp  = (ushort*)(ws + OFF_INV);
  int*    cnt   = (int*)   (ws + OFF_CNT);
  float*  b1p   = (float*) (ws + OFF_B1P);
  ushort* qkv   = (ushort*)(ws + OFF_QKV);
  ushort* ctx   = (ushort*)(ws + OFF_CTX);
  ushort* xn1   = (ushort*)(ws + OFF_XN1);
  ushort* hidden= (ushort*)(ws + OFF_QKV);
  ushort* outC  = (ushort*)(ws + OFF_OUTC);

  ushort* pWqkv = pool + 0;
  ushort* pWo   = pool + 1769472;
  ushort* pSw1  = pool + 2359296;
  ushort* pSw2  = pool + 9437184;
  ushort* pGw1  = pool + 16515072;
  ushort* pGw2  = pool + 35389440;

  const int tier = (ws_size >= (size_t)WS_BIG) ? 2 : ((ws_size >= (size_t)WS_GROUPED) ? 1 : 0);

  // fused preprocessing: weight conversion + b1 fold + LN1 (independent, one launch)
  { PreArgs pa{};
    pa.wqkv=wqkv; pa.wo=wo; pa.sw1=sw1; pa.sw2=sw2; pa.gw1=gw1; pa.gw2=gw2;
    pa.slg=slg; pa.glg=glg; pa.sb1=sb1; pa.gb1=gb1; pa.slb=slb; pa.glb=glb;
    pa.x=x; pa.n1g=n1g; pa.n1b=n1b;
    pa.pool=pool; pa.b1p=b1p; pa.xn1=xn1;
    pre_k<<<63488, 256, 0, stream>>>(pa); }

  { GemmArgs a{}; a.A=xn1; a.B=pWqkv; a.bias=bqkv; a.outBF=qkv; a.K=768; a.ldc=2304;
    gemm_k<<<dim3(64,18),256,0,stream>>>(a); }
  attn_k<<<dim3(16,96),256,0,stream>>>(qkv, ctx);

  FArgs fa{};
  fa.z=z; fa.hidden=hidden; fa.ctx=ctx; fa.wo=pWo; fa.out=out; fa.outC=outC;
  fa.xres=x; fa.bo=bo;
  fa.lists=lists; fa.inv=invp; fa.cnt=cnt; fa.coef=coef;
  fa.sw1=pSw1; fa.gw1=pGw1; fa.sw2=pSw2; fa.gw2=pGw2;
  fa.b1p=b1p; fa.sb2=sb2; fa.gb2=gb2;

  // out-proj with fused residual+bias: dense 2D grid
  { FArgs a = fa; a.jobBase = -1; a.compact = 0; a.mode = 0;
    ffn2_k<<<dim3(128,6),256,0,stream>>>(a); }

  lnr_k<<<2048,256,0,stream>>>(out, n2g, n2b, rw, rb, z, coef);
  build_lists<<<10,256,0,stream>>>(mt, coef, lists, invp, cnt);

  if (tier==2){
    { FArgs a = fa; a.jobBase = 0; a.compact = 1; a.mode = 1;
      a.npanels = 36; ffn1_k<<<2560,512,0,stream>>>(a);
      a.npanels = 18; a.kpx = 3; ffn2_k<<<3072,256,0,stream>>>(a); }
    gather_k<<<2048,256,0,stream>>>(coef, mt, invp, cnt, outC, out, 0);
    { FArgs a = fa; a.jobBase = 3; a.compact = 1; a.mode = 1;
      a.npanels = 96; ffn1_k<<<6144,512,0,stream>>>(a);
      a.npanels = 48; a.kpx = 6; ffn2_k<<<6144,256,0,stream>>>(a); }
    gather_k<<<2048,256,0,stream>>>(coef, mt, invp, cnt, outC, out, 1);
  } else if (tier==1){
    { FArgs a = fa; a.jobBase = 0; a.compact = 1; a.mode = 0;
      a.npanels = 36; ffn1_k<<<2560,512,0,stream>>>(a);
      a.npanels = 18; a.kpx = 3; ffn2_k<<<3072,256,0,stream>>>(a); }
    { FArgs a = fa; a.jobBase = 3; a.compact = 1; a.mode = 0;
      a.npanels = 96; ffn1_k<<<6144,512,0,stream>>>(a);
      a.npanels = 48; a.kpx = 6; ffn2_k<<<6144,256,0,stream>>>(a); }
  } else {
    for (int j=0;j<11;j++){
      FArgs a = fa; a.jobBase = j; a.compact = 0; a.mode = 0;
      a.npanels = 12; ffn1_k<<<1024,512,0,stream>>>(a);
      a.npanels = 6;  a.kpx = 1; ffn2_k<<<1024,256,0,stream>>>(a);
    }
  }
}